// Round 18
// baseline (618.208 us; speedup 1.0000x reference)
//
#include <hip/hip_runtime.h>
#include <hip/hip_bf16.h>

// GAT layer — r17 structure (best: 126.8 us) with REP DIAGNOSTIC on the
// non-att kernels: k_h x12, k_z x30, k_reduce x16 (all idempotent) so each
// dispatch exceeds the ~160 us harness fills and surfaces in rocprof top-5.
// k_att unchanged (REP=1; characterized in r14). Next round reverts REPs.

typedef __attribute__((ext_vector_type(4))) float f32x4;
typedef __attribute__((ext_vector_type(8))) short short8;
typedef __attribute__((ext_vector_type(4))) unsigned short ushort4v;

#define SLOPE 0.1f
#define NROW 8192
#define DDIM 256

__device__ __forceinline__ float lrelu(float x){ return fmaxf(x, SLOPE * x); }

__device__ __forceinline__ unsigned short f2bf(float f){
  union { float f; unsigned u; } v; v.f = f;
  unsigned r = (v.u + 0x7fffu + ((v.u >> 16) & 1u)) >> 16;
  return (unsigned short)r;
}
__device__ __forceinline__ float bf2f(unsigned short u){
  union { unsigned u; float f; } v; v.u = (unsigned)u << 16; return v.f;
}
__device__ __forceinline__ unsigned cvt_pk_bf16(float lo, float hi){
  unsigned r;
  asm("v_cvt_pk_bf16_f32 %0, %1, %2" : "=v"(r) : "v"(lo), "v"(hi));
  return r;
}

// ---------------- K0: Wt_hi/Wt_lo [256][512] bf16 split-transpose of W ----------------
__global__ __launch_bounds__(256) void k_prep(
    const float* __restrict__ W,
    unsigned short* __restrict__ Wt_hi, unsigned short* __restrict__ Wt_lo)
{
  const int tid = blockIdx.x * 256 + threadIdx.x;   // 32768 total
  const int c = tid >> 7, kq = tid & 127;
  ushort4v hi, lo;
#pragma unroll
  for (int j = 0; j < 4; ++j) {
    const float v = W[(size_t)(kq * 4 + j) * 256 + c];
    hi[j] = f2bf(v);
    lo[j] = f2bf(v - bf2f(hi[j]));
  }
  *reinterpret_cast<ushort4v*>(Wt_hi + (size_t)c * 512 + kq * 4) = hi;
  *reinterpret_cast<ushort4v*>(Wt_lo + (size_t)c * 512 + kq * 4) = lo;
}

// ---------------- K1: h-tile via split MFMA; fused s1/s2/e2/e02 + ht bf16 (REP x12) ----------------
__global__ __launch_bounds__(512, 2) void k_h(
    const float* __restrict__ doc, const unsigned short* __restrict__ Wt_hi,
    const unsigned short* __restrict__ Wt_lo, const float* __restrict__ Wb,
    const float* __restrict__ a,
    unsigned short* __restrict__ ht, float* __restrict__ s1,
    float* __restrict__ e2, float* __restrict__ e02)
{
  __shared__ __align__(16) short8 aH[2][2][64];
  __shared__ __align__(16) short8 aL[2][2][64];
  __shared__ float sred[8][2][32];

  const int t = threadIdx.x, w = t >> 6, l = t & 63;
  const int lr = l & 15, lg = l >> 4;
  const int rb = blockIdx.x * 32;
  const int cb = w * 32;

  const float* docp = doc + (size_t)(rb + w * 16 + lr) * 512 + lg * 8;  // valid for w<2

  f32x4 v0, v1;
  auto loadDoc = [&](int k0) { if (w < 2) {
      v0 = *reinterpret_cast<const f32x4*>(docp + k0);
      v1 = *reinterpret_cast<const f32x4*>(docp + k0 + 4);
  }};
  auto writeStage = [&](int pb) { if (w < 2) {
      union { short8 v; unsigned short u[8]; } hi, lo;
#pragma unroll
      for (int q = 0; q < 4; ++q) {
        hi.u[q] = f2bf(v0[q]);     lo.u[q] = f2bf(v0[q] - bf2f(hi.u[q]));
        hi.u[4+q] = f2bf(v1[q]);   lo.u[4+q] = f2bf(v1[q] - bf2f(hi.u[4+q]));
      }
      aH[pb][w][l] = hi.v;
      aL[pb][w][l] = lo.v;
  }};

  for (int rep = 0; rep < 12; ++rep) {      // DIAGNOSTIC (idempotent)
  f32x4 acc[2][2];
#pragma unroll
  for (int rt = 0; rt < 2; ++rt)
#pragma unroll
    for (int ct = 0; ct < 2; ++ct) acc[rt][ct] = (f32x4){0.f, 0.f, 0.f, 0.f};

  __syncthreads();
  loadDoc(0); writeStage(0); loadDoc(32);

  for (int n = 0; n < 16; ++n) {
    const int kk = n * 32;
    const int par = n & 1;

    asm volatile("s_waitcnt lgkmcnt(0)\n\ts_barrier" ::: "memory");

    const short8 ah0 = aH[par][0][l];
    const short8 ah1 = aH[par][1][l];
    const short8 al0 = aL[par][0][l];
    const short8 al1 = aL[par][1][l];

    short8 bh[2], bl[2];
#pragma unroll
    for (int ct = 0; ct < 2; ++ct) {
      const size_t off = (size_t)(cb + ct * 16 + lr) * 512 + kk + lg * 8;
      bh[ct] = *reinterpret_cast<const short8*>(Wt_hi + off);
      bl[ct] = *reinterpret_cast<const short8*>(Wt_lo + off);
    }

    if (n + 1 < 16) writeStage(par ^ 1);
    if (n + 2 < 16) loadDoc((n + 2) * 32);

#pragma unroll
    for (int ct = 0; ct < 2; ++ct) {
      acc[0][ct] = __builtin_amdgcn_mfma_f32_16x16x32_bf16(ah0, bh[ct], acc[0][ct], 0, 0, 0);
      acc[1][ct] = __builtin_amdgcn_mfma_f32_16x16x32_bf16(ah1, bh[ct], acc[1][ct], 0, 0, 0);
      acc[0][ct] = __builtin_amdgcn_mfma_f32_16x16x32_bf16(ah0, bl[ct], acc[0][ct], 0, 0, 0);
      acc[1][ct] = __builtin_amdgcn_mfma_f32_16x16x32_bf16(ah1, bl[ct], acc[1][ct], 0, 0, 0);
      acc[0][ct] = __builtin_amdgcn_mfma_f32_16x16x32_bf16(al0, bh[ct], acc[0][ct], 0, 0, 0);
      acc[1][ct] = __builtin_amdgcn_mfma_f32_16x16x32_bf16(al1, bh[ct], acc[1][ct], 0, 0, 0);
    }
  }

  float bias[2];
#pragma unroll
  for (int ct = 0; ct < 2; ++ct) bias[ct] = Wb[cb + ct * 16 + lr];
#pragma unroll
  for (int rt = 0; rt < 2; ++rt)
#pragma unroll
    for (int ct = 0; ct < 2; ++ct) {
#pragma unroll
      for (int q = 0; q < 4; ++q) acc[rt][ct][q] += bias[ct];
      ushort4v u;
#pragma unroll
      for (int q = 0; q < 4; ++q) u[q] = f2bf(acc[rt][ct][q]);
      *reinterpret_cast<ushort4v*>(
          ht + (size_t)(cb + ct * 16 + lr) * 8192 + rb + rt * 16 + lg * 4) = u;
    }

  float a1c[2], a2c[2];
#pragma unroll
  for (int ct = 0; ct < 2; ++ct) {
    a1c[ct] = a[cb + ct * 16 + lr];
    a2c[ct] = a[256 + cb + ct * 16 + lr];
  }
  float p1[2][4], p2[2][4];
#pragma unroll
  for (int rt = 0; rt < 2; ++rt)
#pragma unroll
    for (int q = 0; q < 4; ++q) {
      float x1 = 0.f, x2 = 0.f;
#pragma unroll
      for (int ct = 0; ct < 2; ++ct) {
        x1 = fmaf(acc[rt][ct][q], a1c[ct], x1);
        x2 = fmaf(acc[rt][ct][q], a2c[ct], x2);
      }
#pragma unroll
      for (int off = 1; off < 16; off <<= 1) {
        x1 += __shfl_xor(x1, off);
        x2 += __shfl_xor(x2, off);
      }
      p1[rt][q] = x1; p2[rt][q] = x2;
    }
  __syncthreads();
  if (lr == 0) {
#pragma unroll
    for (int rt = 0; rt < 2; ++rt)
#pragma unroll
      for (int q = 0; q < 4; ++q) {
        sred[w][0][rt * 16 + lg * 4 + q] = p1[rt][q];
        sred[w][1][rt * 16 + lg * 4 + q] = p2[rt][q];
      }
  }
  __syncthreads();
  if (t < 32) {
    float v1s = 0.f, v2s = 0.f;
#pragma unroll
    for (int ww = 0; ww < 8; ++ww) { v1s += sred[ww][0][t]; v2s += sred[ww][1][t]; }
    const int r = rb + t;
    s1[r] = v1s;
    e2[r] = __expf(v2s);
    e02[r] = __expf(SLOPE * v2s);
  }
  }  // rep
}

// ---------------- K3: per-row Z -> rowinfo (REP x30) ----------------
__global__ __launch_bounds__(256) void k_z(
    const float* __restrict__ s1, const float* __restrict__ e2g,
    const float* __restrict__ e02g, const float* __restrict__ abp,
    float* __restrict__ rowinfo)
{
  __shared__ __align__(16) float es[8192];
  __shared__ __align__(16) float fs[8192];
  const int t = threadIdx.x;
  const int w = t >> 6, l = t & 63;
  const int rb = blockIdx.x * 16 + w * 4;

  for (int rep = 0; rep < 30; ++rep) {      // DIAGNOSTIC (idempotent)
  for (int i = t * 4; i < 8192; i += 1024) {
    *reinterpret_cast<f32x4*>(&es[i]) = *reinterpret_cast<const f32x4*>(e2g + i);
    *reinterpret_cast<f32x4*>(&fs[i]) = *reinterpret_cast<const f32x4*>(e02g + i);
  }
  __syncthreads();
  const float ab = abp[0];
  float T[4], E1[4], E01[4];
#pragma unroll
  for (int rr = 0; rr < 4; ++rr) {
    const float s1a = s1[rb + rr] + ab;
    E1[rr] = __expf(s1a); E01[rr] = __expf(SLOPE * s1a); T[rr] = __expf(-s1a);
  }
  float zA[4] = {0.f,0.f,0.f,0.f}, zB[4] = {0.f,0.f,0.f,0.f};
  for (int i = l * 4; i < 8192; i += 256) {
    const f32x4 e = *reinterpret_cast<const f32x4*>(&es[i]);
    const f32x4 f = *reinterpret_cast<const f32x4*>(&fs[i]);
#pragma unroll
    for (int rr = 0; rr < 4; ++rr)
#pragma unroll
      for (int q = 0; q < 4; ++q) {
        const bool c = (e[q] >= T[rr]);
        zA[rr] += c ? e[q] : 0.f;
        zB[rr] += c ? 0.f : f[q];
      }
  }
#pragma unroll
  for (int rr = 0; rr < 4; ++rr) {
    float z = E1[rr] * zA[rr] + E01[rr] * zB[rr];
#pragma unroll
    for (int off = 32; off > 0; off >>= 1) z += __shfl_down(z, off);
    if (l == 0) {
      const float iz = 1.0f / z;
      f32x4 ri = (f32x4){E1[rr] * iz, E01[rr] * iz, T[rr], iz};
      *reinterpret_cast<f32x4*>(rowinfo + (size_t)(rb + rr) * 4) = ri;
    }
  }
  __syncthreads();
  }  // rep
}

// ---------------- K4: att + partial out via MFMA; gen2 bursts + rotated k-order ----------------
__global__ __launch_bounds__(512, 4) void k_att(
    const float* __restrict__ rowinfo, const float* __restrict__ e2g,
    const float* __restrict__ e02g, const unsigned short* __restrict__ ht,
    float* __restrict__ att, float* __restrict__ part, int CHUNK)
{
  extern __shared__ __align__(16) char smem[];
  char* plsb  = smem;                                    // [4][4][64] short8 = 16 KB
  float* e2s  = reinterpret_cast<float*>(smem + 16384);  // CHUNK
  float* e02s = e2s + CHUNK;                             // CHUNK

  const int t = threadIdx.x, w = t >> 6, l = t & 63;
  const int lr = l & 15, lg = l >> 4;
  const int kbase = blockIdx.x * CHUNK;     // slice (fastest -> XCD)
  const int rb = blockIdx.y * 64;

  for (int i = t * 4; i < CHUNK; i += 2048) {
    *reinterpret_cast<f32x4*>(e2s + i)  = *reinterpret_cast<const f32x4*>(e2g + kbase + i);
    *reinterpret_cast<f32x4*>(e02s + i) = *reinterpret_cast<const f32x4*>(e02g + kbase + i);
  }

  const int r = l >> 3, jc = l & 7;
  const int rowW = rb + w * 8 + r;
  const f32x4 ri = *reinterpret_cast<const f32x4*>(rowinfo + (size_t)rowW * 4);
  const float E1z = ri[0], E01z = ri[1], T = ri[2];
  float* attW = att + (size_t)rowW * 8192 + kbase + jc * 4;
  const int fragoff = (w >> 1) * 1024 + ((jc >> 1) * 16 + (w & 1) * 8 + r) * 16 + (jc & 1) * 8;

  __syncthreads();

  auto gen2 = [&](int kw, int pb0, int pb1) {
    const f32x4 eA = *reinterpret_cast<const f32x4*>(e2s + kw + jc * 4);
    const f32x4 fA = *reinterpret_cast<const f32x4*>(e02s + kw + jc * 4);
    const f32x4 eB = *reinterpret_cast<const f32x4*>(e2s + kw + 32 + jc * 4);
    const f32x4 fB = *reinterpret_cast<const f32x4*>(e02s + kw + 32 + jc * 4);
    f32x4 pA, pB;
#pragma unroll
    for (int q = 0; q < 4; ++q) {
      const bool cA = (eA[q] >= T);
      pA[q] = (cA ? E1z : E01z) * (cA ? eA[q] : fA[q]);
      const bool cB = (eB[q] >= T);
      pB[q] = (cB ? E1z : E01z) * (cB ? eB[q] : fB[q]);
    }
    __builtin_nontemporal_store(pA, reinterpret_cast<f32x4*>(attW + kw));
    __builtin_nontemporal_store(pB, reinterpret_cast<f32x4*>(attW + kw + 32));
    uint2 uA, uB;
    uA.x = cvt_pk_bf16(pA[0], pA[1]); uA.y = cvt_pk_bf16(pA[2], pA[3]);
    uB.x = cvt_pk_bf16(pB[0], pB[1]); uB.y = cvt_pk_bf16(pB[2], pB[3]);
    *reinterpret_cast<uint2*>(plsb + pb0 * 4096 + fragoff) = uA;
    *reinterpret_cast<uint2*>(plsb + pb1 * 4096 + fragoff) = uB;
  };

  const unsigned short* hbase = ht + (size_t)(w * 32 + lr) * 8192 + kbase + lg * 8;
  auto loadB = [&](short8* b, int n) {
    const int kk = n * 32;
    b[0] = *reinterpret_cast<const short8*>(hbase + kk);
    b[1] = *reinterpret_cast<const short8*>(hbase + kk + (size_t)16 * 8192);
  };

  f32x4 acc[4][2];
#pragma unroll
  for (int rt = 0; rt < 4; ++rt)
#pragma unroll
    for (int ct = 0; ct < 2; ++ct) acc[rt][ct] = (f32x4){0.f, 0.f, 0.f, 0.f};

  auto mma = [&](const short8* b, const short8& af0, const short8& af1,
                 const short8& af2, const short8& af3) {
    __builtin_amdgcn_s_setprio(1);
    acc[0][0] = __builtin_amdgcn_mfma_f32_16x16x32_bf16(af0, b[0], acc[0][0], 0, 0, 0);
    acc[1][0] = __builtin_amdgcn_mfma_f32_16x16x32_bf16(af1, b[0], acc[1][0], 0, 0, 0);
    acc[2][0] = __builtin_amdgcn_mfma_f32_16x16x32_bf16(af2, b[0], acc[2][0], 0, 0, 0);
    acc[3][0] = __builtin_amdgcn_mfma_f32_16x16x32_bf16(af3, b[0], acc[3][0], 0, 0, 0);
    acc[0][1] = __builtin_amdgcn_mfma_f32_16x16x32_bf16(af0, b[1], acc[0][1], 0, 0, 0);
    acc[1][1] = __builtin_amdgcn_mfma_f32_16x16x32_bf16(af1, b[1], acc[1][1], 0, 0, 0);
    acc[2][1] = __builtin_amdgcn_mfma_f32_16x16x32_bf16(af2, b[1], acc[2][1], 0, 0, 0);
    acc[3][1] = __builtin_amdgcn_mfma_f32_16x16x32_bf16(af3, b[1], acc[3][1], 0, 0, 0);
    __builtin_amdgcn_s_setprio(0);
  };

  const int NIT = CHUNK / 32;                 // even (64 at KS=4)
  const int ro = ((blockIdx.y * 29) % (NIT / 2)) * 2;
  auto MW = [&](int n) { return (n + ro) % NIT; };

  short8 bAr[2], bBr[2];
  loadB(bAr, MW(0));
  gen2(MW(0) * 32, 0, 1);

  for (int n = 0; n < NIT; n += 2) {
    loadB(bBr, MW(n + 1));
    asm volatile("s_waitcnt lgkmcnt(0)\n\ts_barrier" ::: "memory");
    {
      const short8* pbuf = reinterpret_cast<const short8*>(plsb + (size_t)(n & 3) * 4096);
      const short8 af0 = pbuf[0 * 64 + l];
      const short8 af1 = pbuf[1 * 64 + l];
      const short8 af2 = pbuf[2 * 64 + l];
      const short8 af3 = pbuf[3 * 64 + l];
      if (n + 2 < NIT) gen2(MW(n + 2) * 32, (n + 2) & 3, (n + 3) & 3);
      mma(bAr, af0, af1, af2, af3);
    }
    if (n + 2 < NIT) loadB(bAr, MW(n + 2));
    asm volatile("s_waitcnt lgkmcnt(0)\n\ts_barrier" ::: "memory");
    {
      const short8* pbuf = reinterpret_cast<const short8*>(plsb + (size_t)((n + 1) & 3) * 4096);
      const short8 af0 = pbuf[0 * 64 + l];
      const short8 af1 = pbuf[1 * 64 + l];
      const short8 af2 = pbuf[2 * 64 + l];
      const short8 af3 = pbuf[3 * 64 + l];
      mma(bBr, af0, af1, af2, af3);
    }
  }

  float* pb = part + (size_t)blockIdx.x * ((size_t)NROW * DDIM);
#pragma unroll
  for (int rt = 0; rt < 4; ++rt)
#pragma unroll
    for (int ct = 0; ct < 2; ++ct)
#pragma unroll
      for (int q = 0; q < 4; ++q)
        __builtin_nontemporal_store(acc[rt][ct][q],
            pb + (size_t)(rb + rt * 16 + lg * 4 + q) * 256 + w * 32 + ct * 16 + lr);
}

// ---------------- K5: out = lrelu(sum_k part[k]) (REP x16) ----------------
__global__ __launch_bounds__(256) void k_reduce(
    const float* __restrict__ part, float* __restrict__ out, int KS)
{
  const size_t idx = ((size_t)blockIdx.x * 256 + threadIdx.x) * 4;
  for (int rep = 0; rep < 16; ++rep) {      // DIAGNOSTIC (idempotent)
    f32x4 s = __builtin_nontemporal_load(reinterpret_cast<const f32x4*>(part + idx));
    for (int k = 1; k < KS; ++k) {
      const f32x4 v = __builtin_nontemporal_load(
          reinterpret_cast<const f32x4*>(part + (size_t)k * NROW * DDIM + idx));
#pragma unroll
      for (int q = 0; q < 4; ++q) s[q] += v[q];
    }
#pragma unroll
    for (int q = 0; q < 4; ++q) s[q] = lrelu(s[q]);
    __builtin_nontemporal_store(s, reinterpret_cast<f32x4*>(out + idx));
  }
}

extern "C" void kernel_launch(void* const* d_in, const int* in_sizes, int n_in,
                              void* d_out, int out_size, void* d_ws, size_t ws_size,
                              hipStream_t stream)
{
  const float* doc = (const float*)d_in[0];
  const float* W   = (const float*)d_in[1];
  const float* Wb  = (const float*)d_in[2];
  const float* a   = (const float*)d_in[3];
  const float* ab  = (const float*)d_in[4];

  float* out = (float*)d_out;                 // 8192*256
  float* att = out + (size_t)8192 * 256;      // 8192*8192

  char* ws = (char*)d_ws;
  unsigned short* ht    = (unsigned short*)ws;                              // 4 MB
  unsigned short* Wt_hi = (unsigned short*)(ws + (size_t)4 * 1024 * 1024);  // 256 KB
  unsigned short* Wt_lo = Wt_hi + (size_t)256 * 512;                        // 256 KB
  float* s1      = (float*)(ws + (size_t)4 * 1024 * 1024 + 512 * 1024);     // 32 KB
  float* e2      = s1 + 8192;
  float* e02     = e2 + 8192;
  float* rowinfo = e02 + 8192;                                              // 128 KB
  const size_t base = (size_t)5 * 1024 * 1024;
  const size_t partBytes = (size_t)NROW * DDIM * sizeof(float);             // 8 MB

  int KS = 1;
  for (int c = 4; c >= 1; c >>= 1)
    if (base + (size_t)c * partBytes <= ws_size) { KS = c; break; }
  float* part = (float*)(ws + base);
  const int CHUNK = NROW / KS;
  const size_t smem = 16384 + (size_t)2 * CHUNK * sizeof(float);

  hipLaunchKernelGGL(k_prep,   dim3(128),     dim3(256), 0,    stream, W, Wt_hi, Wt_lo);
  hipLaunchKernelGGL(k_h,      dim3(256),     dim3(512), 0,    stream, doc, Wt_hi, Wt_lo, Wb, a, ht, s1, e2, e02);
  hipLaunchKernelGGL(k_z,      dim3(512),     dim3(256), 0,    stream, s1, e2, e02, ab, rowinfo);
  hipLaunchKernelGGL(k_att,    dim3(KS, 128), dim3(512), smem, stream, rowinfo, e2, e02, ht, att, part, CHUNK);
  hipLaunchKernelGGL(k_reduce, dim3(2048),    dim3(256), 0,    stream, part, out, KS);
}

// Round 19
// 324.844 us; speedup vs baseline: 1.9031x; 1.9031x over previous
//
#include <hip/hip_runtime.h>
#include <hip/hip_bf16.h>

// GAT layer — r17 structure (best: 126.8 us), single structural change:
// k_reduce FUSED into k_att via last-block reduction (device-scope fence +
// per-rowblock atomic counter; finisher sums KS slices, lrelu, writes out,
// resets counter for graph replay). Removes 1 dispatch + inter-kernel gap.
// r18 diagnostic: k_z 9.8us @99.6% VALU, k_h ~9, k_reduce ~7 (BW roofline),
// k_att ~62-65 (pattern ceiling ~4.7 TB/s), gaps ~34us across 5 dispatches.

typedef __attribute__((ext_vector_type(4))) float f32x4;
typedef __attribute__((ext_vector_type(8))) short short8;
typedef __attribute__((ext_vector_type(4))) unsigned short ushort4v;

#define SLOPE 0.1f
#define NROW 8192
#define DDIM 256

__device__ __forceinline__ float lrelu(float x){ return fmaxf(x, SLOPE * x); }

__device__ __forceinline__ unsigned short f2bf(float f){
  union { float f; unsigned u; } v; v.f = f;
  unsigned r = (v.u + 0x7fffu + ((v.u >> 16) & 1u)) >> 16;
  return (unsigned short)r;
}
__device__ __forceinline__ float bf2f(unsigned short u){
  union { unsigned u; float f; } v; v.u = (unsigned)u << 16; return v.f;
}
__device__ __forceinline__ unsigned cvt_pk_bf16(float lo, float hi){
  unsigned r;
  asm("v_cvt_pk_bf16_f32 %0, %1, %2" : "=v"(r) : "v"(lo), "v"(hi));
  return r;
}

// ---------------- K0: Wt split-transpose + zero the reduction counters ----------------
__global__ __launch_bounds__(256) void k_prep(
    const float* __restrict__ W,
    unsigned short* __restrict__ Wt_hi, unsigned short* __restrict__ Wt_lo,
    int* __restrict__ cnt)
{
  const int tid = blockIdx.x * 256 + threadIdx.x;   // 32768 total
  if (tid < 128) cnt[tid] = 0;
  const int c = tid >> 7, kq = tid & 127;
  ushort4v hi, lo;
#pragma unroll
  for (int j = 0; j < 4; ++j) {
    const float v = W[(size_t)(kq * 4 + j) * 256 + c];
    hi[j] = f2bf(v);
    lo[j] = f2bf(v - bf2f(hi[j]));
  }
  *reinterpret_cast<ushort4v*>(Wt_hi + (size_t)c * 512 + kq * 4) = hi;
  *reinterpret_cast<ushort4v*>(Wt_lo + (size_t)c * 512 + kq * 4) = lo;
}

// ---------------- K1: h-tile via split MFMA; fused s1/s2/e2/e02 + ht bf16 ----------------
__global__ __launch_bounds__(512, 2) void k_h(
    const float* __restrict__ doc, const unsigned short* __restrict__ Wt_hi,
    const unsigned short* __restrict__ Wt_lo, const float* __restrict__ Wb,
    const float* __restrict__ a,
    unsigned short* __restrict__ ht, float* __restrict__ s1,
    float* __restrict__ e2, float* __restrict__ e02)
{
  __shared__ __align__(16) short8 aH[2][2][64];
  __shared__ __align__(16) short8 aL[2][2][64];
  __shared__ float sred[8][2][32];

  const int t = threadIdx.x, w = t >> 6, l = t & 63;
  const int lr = l & 15, lg = l >> 4;
  const int rb = blockIdx.x * 32;
  const int cb = w * 32;

  f32x4 acc[2][2];
#pragma unroll
  for (int rt = 0; rt < 2; ++rt)
#pragma unroll
    for (int ct = 0; ct < 2; ++ct) acc[rt][ct] = (f32x4){0.f, 0.f, 0.f, 0.f};

  const float* docp = doc + (size_t)(rb + w * 16 + lr) * 512 + lg * 8;  // valid for w<2

  f32x4 v0, v1;
  auto loadDoc = [&](int k0) { if (w < 2) {
      v0 = *reinterpret_cast<const f32x4*>(docp + k0);
      v1 = *reinterpret_cast<const f32x4*>(docp + k0 + 4);
  }};
  auto writeStage = [&](int pb) { if (w < 2) {
      union { short8 v; unsigned short u[8]; } hi, lo;
#pragma unroll
      for (int q = 0; q < 4; ++q) {
        hi.u[q] = f2bf(v0[q]);     lo.u[q] = f2bf(v0[q] - bf2f(hi.u[q]));
        hi.u[4+q] = f2bf(v1[q]);   lo.u[4+q] = f2bf(v1[q] - bf2f(hi.u[4+q]));
      }
      aH[pb][w][l] = hi.v;
      aL[pb][w][l] = lo.v;
  }};

  loadDoc(0); writeStage(0); loadDoc(32);

  for (int n = 0; n < 16; ++n) {
    const int kk = n * 32;
    const int par = n & 1;

    asm volatile("s_waitcnt lgkmcnt(0)\n\ts_barrier" ::: "memory");

    const short8 ah0 = aH[par][0][l];
    const short8 ah1 = aH[par][1][l];
    const short8 al0 = aL[par][0][l];
    const short8 al1 = aL[par][1][l];

    short8 bh[2], bl[2];
#pragma unroll
    for (int ct = 0; ct < 2; ++ct) {
      const size_t off = (size_t)(cb + ct * 16 + lr) * 512 + kk + lg * 8;
      bh[ct] = *reinterpret_cast<const short8*>(Wt_hi + off);
      bl[ct] = *reinterpret_cast<const short8*>(Wt_lo + off);
    }

    if (n + 1 < 16) writeStage(par ^ 1);
    if (n + 2 < 16) loadDoc((n + 2) * 32);

#pragma unroll
    for (int ct = 0; ct < 2; ++ct) {
      acc[0][ct] = __builtin_amdgcn_mfma_f32_16x16x32_bf16(ah0, bh[ct], acc[0][ct], 0, 0, 0);
      acc[1][ct] = __builtin_amdgcn_mfma_f32_16x16x32_bf16(ah1, bh[ct], acc[1][ct], 0, 0, 0);
      acc[0][ct] = __builtin_amdgcn_mfma_f32_16x16x32_bf16(ah0, bl[ct], acc[0][ct], 0, 0, 0);
      acc[1][ct] = __builtin_amdgcn_mfma_f32_16x16x32_bf16(ah1, bl[ct], acc[1][ct], 0, 0, 0);
      acc[0][ct] = __builtin_amdgcn_mfma_f32_16x16x32_bf16(al0, bh[ct], acc[0][ct], 0, 0, 0);
      acc[1][ct] = __builtin_amdgcn_mfma_f32_16x16x32_bf16(al1, bh[ct], acc[1][ct], 0, 0, 0);
    }
  }

  float bias[2];
#pragma unroll
  for (int ct = 0; ct < 2; ++ct) bias[ct] = Wb[cb + ct * 16 + lr];
#pragma unroll
  for (int rt = 0; rt < 2; ++rt)
#pragma unroll
    for (int ct = 0; ct < 2; ++ct) {
#pragma unroll
      for (int q = 0; q < 4; ++q) acc[rt][ct][q] += bias[ct];
      ushort4v u;
#pragma unroll
      for (int q = 0; q < 4; ++q) u[q] = f2bf(acc[rt][ct][q]);
      *reinterpret_cast<ushort4v*>(
          ht + (size_t)(cb + ct * 16 + lr) * 8192 + rb + rt * 16 + lg * 4) = u;
    }

  float a1c[2], a2c[2];
#pragma unroll
  for (int ct = 0; ct < 2; ++ct) {
    a1c[ct] = a[cb + ct * 16 + lr];
    a2c[ct] = a[256 + cb + ct * 16 + lr];
  }
  float p1[2][4], p2[2][4];
#pragma unroll
  for (int rt = 0; rt < 2; ++rt)
#pragma unroll
    for (int q = 0; q < 4; ++q) {
      float x1 = 0.f, x2 = 0.f;
#pragma unroll
      for (int ct = 0; ct < 2; ++ct) {
        x1 = fmaf(acc[rt][ct][q], a1c[ct], x1);
        x2 = fmaf(acc[rt][ct][q], a2c[ct], x2);
      }
#pragma unroll
      for (int off = 1; off < 16; off <<= 1) {
        x1 += __shfl_xor(x1, off);
        x2 += __shfl_xor(x2, off);
      }
      p1[rt][q] = x1; p2[rt][q] = x2;
    }
  __syncthreads();
  if (lr == 0) {
#pragma unroll
    for (int rt = 0; rt < 2; ++rt)
#pragma unroll
      for (int q = 0; q < 4; ++q) {
        sred[w][0][rt * 16 + lg * 4 + q] = p1[rt][q];
        sred[w][1][rt * 16 + lg * 4 + q] = p2[rt][q];
      }
  }
  __syncthreads();
  if (t < 32) {
    float v1s = 0.f, v2s = 0.f;
#pragma unroll
    for (int ww = 0; ww < 8; ++ww) { v1s += sred[ww][0][t]; v2s += sred[ww][1][t]; }
    const int r = rb + t;
    s1[r] = v1s;
    e2[r] = __expf(v2s);
    e02[r] = __expf(SLOPE * v2s);
  }
}

// ---------------- K3: per-row Z -> rowinfo {E1*iz, E01*iz, T, iz} ----------------
__global__ __launch_bounds__(256) void k_z(
    const float* __restrict__ s1, const float* __restrict__ e2g,
    const float* __restrict__ e02g, const float* __restrict__ abp,
    float* __restrict__ rowinfo)
{
  __shared__ __align__(16) float es[8192];
  __shared__ __align__(16) float fs[8192];
  const int t = threadIdx.x;
  for (int i = t * 4; i < 8192; i += 1024) {
    *reinterpret_cast<f32x4*>(&es[i]) = *reinterpret_cast<const f32x4*>(e2g + i);
    *reinterpret_cast<f32x4*>(&fs[i]) = *reinterpret_cast<const f32x4*>(e02g + i);
  }
  __syncthreads();
  const int w = t >> 6, l = t & 63;
  const float ab = abp[0];
  const int rb = blockIdx.x * 16 + w * 4;
  float T[4], E1[4], E01[4];
#pragma unroll
  for (int rr = 0; rr < 4; ++rr) {
    const float s1a = s1[rb + rr] + ab;
    E1[rr] = __expf(s1a); E01[rr] = __expf(SLOPE * s1a); T[rr] = __expf(-s1a);
  }
  float zA[4] = {0.f,0.f,0.f,0.f}, zB[4] = {0.f,0.f,0.f,0.f};
  for (int i = l * 4; i < 8192; i += 256) {
    const f32x4 e = *reinterpret_cast<const f32x4*>(&es[i]);
    const f32x4 f = *reinterpret_cast<const f32x4*>(&fs[i]);
#pragma unroll
    for (int rr = 0; rr < 4; ++rr)
#pragma unroll
      for (int q = 0; q < 4; ++q) {
        const bool c = (e[q] >= T[rr]);
        zA[rr] += c ? e[q] : 0.f;
        zB[rr] += c ? 0.f : f[q];
      }
  }
#pragma unroll
  for (int rr = 0; rr < 4; ++rr) {
    float z = E1[rr] * zA[rr] + E01[rr] * zB[rr];
#pragma unroll
    for (int off = 32; off > 0; off >>= 1) z += __shfl_down(z, off);
    if (l == 0) {
      const float iz = 1.0f / z;
      f32x4 ri = (f32x4){E1[rr] * iz, E01[rr] * iz, T[rr], iz};
      *reinterpret_cast<f32x4*>(rowinfo + (size_t)(rb + rr) * 4) = ri;
    }
  }
}

// ---------------- K4: att + partial + FUSED last-block reduction ----------------
// grid (KS, 128), block 512 = 8 waves. r17 body (gen2 bursts, rotated k-order).
// Epilogue: plain partial stores, __threadfence, atomicAdd(cnt[rowblock]);
// the KS-th finisher sums all slices for its 64 rows, lrelu -> out, resets cnt.
__global__ __launch_bounds__(512, 4) void k_att(
    const float* __restrict__ rowinfo, const float* __restrict__ e2g,
    const float* __restrict__ e02g, const unsigned short* __restrict__ ht,
    float* __restrict__ att, float* __restrict__ part, float* __restrict__ out,
    int* __restrict__ cnt, int CHUNK)
{
  extern __shared__ __align__(16) char smem[];
  char* plsb  = smem;                                    // [4][4][64] short8 = 16 KB
  float* e2s  = reinterpret_cast<float*>(smem + 16384);  // CHUNK
  float* e02s = e2s + CHUNK;                             // CHUNK
  __shared__ int lastFlag;

  const int t = threadIdx.x, w = t >> 6, l = t & 63;
  const int lr = l & 15, lg = l >> 4;
  const int kbase = blockIdx.x * CHUNK;     // slice (fastest -> XCD)
  const int rb = blockIdx.y * 64;

  for (int i = t * 4; i < CHUNK; i += 2048) {
    *reinterpret_cast<f32x4*>(e2s + i)  = *reinterpret_cast<const f32x4*>(e2g + kbase + i);
    *reinterpret_cast<f32x4*>(e02s + i) = *reinterpret_cast<const f32x4*>(e02g + kbase + i);
  }

  const int r = l >> 3, jc = l & 7;
  const int rowW = rb + w * 8 + r;
  const f32x4 ri = *reinterpret_cast<const f32x4*>(rowinfo + (size_t)rowW * 4);
  const float E1z = ri[0], E01z = ri[1], T = ri[2];
  float* attW = att + (size_t)rowW * 8192 + kbase + jc * 4;
  const int fragoff = (w >> 1) * 1024 + ((jc >> 1) * 16 + (w & 1) * 8 + r) * 16 + (jc & 1) * 8;

  __syncthreads();

  auto gen2 = [&](int kw, int pb0, int pb1) {
    const f32x4 eA = *reinterpret_cast<const f32x4*>(e2s + kw + jc * 4);
    const f32x4 fA = *reinterpret_cast<const f32x4*>(e02s + kw + jc * 4);
    const f32x4 eB = *reinterpret_cast<const f32x4*>(e2s + kw + 32 + jc * 4);
    const f32x4 fB = *reinterpret_cast<const f32x4*>(e02s + kw + 32 + jc * 4);
    f32x4 pA, pB;
#pragma unroll
    for (int q = 0; q < 4; ++q) {
      const bool cA = (eA[q] >= T);
      pA[q] = (cA ? E1z : E01z) * (cA ? eA[q] : fA[q]);
      const bool cB = (eB[q] >= T);
      pB[q] = (cB ? E1z : E01z) * (cB ? eB[q] : fB[q]);
    }
    __builtin_nontemporal_store(pA, reinterpret_cast<f32x4*>(attW + kw));
    __builtin_nontemporal_store(pB, reinterpret_cast<f32x4*>(attW + kw + 32));
    uint2 uA, uB;
    uA.x = cvt_pk_bf16(pA[0], pA[1]); uA.y = cvt_pk_bf16(pA[2], pA[3]);
    uB.x = cvt_pk_bf16(pB[0], pB[1]); uB.y = cvt_pk_bf16(pB[2], pB[3]);
    *reinterpret_cast<uint2*>(plsb + pb0 * 4096 + fragoff) = uA;
    *reinterpret_cast<uint2*>(plsb + pb1 * 4096 + fragoff) = uB;
  };

  const unsigned short* hbase = ht + (size_t)(w * 32 + lr) * 8192 + kbase + lg * 8;
  auto loadB = [&](short8* b, int n) {
    const int kk = n * 32;
    b[0] = *reinterpret_cast<const short8*>(hbase + kk);
    b[1] = *reinterpret_cast<const short8*>(hbase + kk + (size_t)16 * 8192);
  };

  f32x4 acc[4][2];
#pragma unroll
  for (int rt = 0; rt < 4; ++rt)
#pragma unroll
    for (int ct = 0; ct < 2; ++ct) acc[rt][ct] = (f32x4){0.f, 0.f, 0.f, 0.f};

  auto mma = [&](const short8* b, const short8& af0, const short8& af1,
                 const short8& af2, const short8& af3) {
    __builtin_amdgcn_s_setprio(1);
    acc[0][0] = __builtin_amdgcn_mfma_f32_16x16x32_bf16(af0, b[0], acc[0][0], 0, 0, 0);
    acc[1][0] = __builtin_amdgcn_mfma_f32_16x16x32_bf16(af1, b[0], acc[1][0], 0, 0, 0);
    acc[2][0] = __builtin_amdgcn_mfma_f32_16x16x32_bf16(af2, b[0], acc[2][0], 0, 0, 0);
    acc[3][0] = __builtin_amdgcn_mfma_f32_16x16x32_bf16(af3, b[0], acc[3][0], 0, 0, 0);
    acc[0][1] = __builtin_amdgcn_mfma_f32_16x16x32_bf16(af0, b[1], acc[0][1], 0, 0, 0);
    acc[1][1] = __builtin_amdgcn_mfma_f32_16x16x32_bf16(af1, b[1], acc[1][1], 0, 0, 0);
    acc[2][1] = __builtin_amdgcn_mfma_f32_16x16x32_bf16(af2, b[1], acc[2][1], 0, 0, 0);
    acc[3][1] = __builtin_amdgcn_mfma_f32_16x16x32_bf16(af3, b[1], acc[3][1], 0, 0, 0);
    __builtin_amdgcn_s_setprio(0);
  };

  const int NIT = CHUNK / 32;                 // even (64 at KS=4)
  const int ro = ((blockIdx.y * 29) % (NIT / 2)) * 2;
  auto MW = [&](int n) { return (n + ro) % NIT; };

  short8 bAr[2], bBr[2];
  loadB(bAr, MW(0));
  gen2(MW(0) * 32, 0, 1);

  for (int n = 0; n < NIT; n += 2) {
    loadB(bBr, MW(n + 1));
    asm volatile("s_waitcnt lgkmcnt(0)\n\ts_barrier" ::: "memory");
    {
      const short8* pbuf = reinterpret_cast<const short8*>(plsb + (size_t)(n & 3) * 4096);
      const short8 af0 = pbuf[0 * 64 + l];
      const short8 af1 = pbuf[1 * 64 + l];
      const short8 af2 = pbuf[2 * 64 + l];
      const short8 af3 = pbuf[3 * 64 + l];
      if (n + 2 < NIT) gen2(MW(n + 2) * 32, (n + 2) & 3, (n + 3) & 3);
      mma(bAr, af0, af1, af2, af3);
    }
    if (n + 2 < NIT) loadB(bAr, MW(n + 2));
    asm volatile("s_waitcnt lgkmcnt(0)\n\ts_barrier" ::: "memory");
    {
      const short8* pbuf = reinterpret_cast<const short8*>(plsb + (size_t)((n + 1) & 3) * 4096);
      const short8 af0 = pbuf[0 * 64 + l];
      const short8 af1 = pbuf[1 * 64 + l];
      const short8 af2 = pbuf[2 * 64 + l];
      const short8 af3 = pbuf[3 * 64 + l];
      mma(bBr, af0, af1, af2, af3);
    }
  }

  // partial sums (plain stores -> device-visible after threadfence)
  float* pb = part + (size_t)blockIdx.x * ((size_t)NROW * DDIM);
#pragma unroll
  for (int rt = 0; rt < 4; ++rt)
#pragma unroll
    for (int ct = 0; ct < 2; ++ct)
#pragma unroll
      for (int q = 0; q < 4; ++q)
        pb[(size_t)(rb + rt * 16 + lg * 4 + q) * 256 + w * 32 + ct * 16 + lr] = acc[rt][ct][q];

  __threadfence();
  if (t == 0) {
    const int old = atomicAdd(&cnt[blockIdx.y], 1);
    lastFlag = (old == (int)gridDim.x - 1) ? 1 : 0;
  }
  __syncthreads();
  if (lastFlag) {
    __threadfence();  // acquire: ensure other slices' partials are visible
    const int KS = (int)gridDim.x;
    const size_t base = (size_t)rb * 256;
    for (int idx = t; idx < 4096; idx += 512) {      // 64 rows x 256 cols / 4
      const size_t off = base + (size_t)idx * 4;
      f32x4 s = *reinterpret_cast<const f32x4*>(part + off);
      for (int k = 1; k < KS; ++k) {
        const f32x4 v = *reinterpret_cast<const f32x4*>(
            part + (size_t)k * NROW * DDIM + off);
#pragma unroll
        for (int q = 0; q < 4; ++q) s[q] += v[q];
      }
#pragma unroll
      for (int q = 0; q < 4; ++q) s[q] = lrelu(s[q]);
      __builtin_nontemporal_store(s, reinterpret_cast<f32x4*>(out + off));
    }
    if (t == 0) cnt[blockIdx.y] = 0;   // reset for next graph replay
  }
}

extern "C" void kernel_launch(void* const* d_in, const int* in_sizes, int n_in,
                              void* d_out, int out_size, void* d_ws, size_t ws_size,
                              hipStream_t stream)
{
  const float* doc = (const float*)d_in[0];
  const float* W   = (const float*)d_in[1];
  const float* Wb  = (const float*)d_in[2];
  const float* a   = (const float*)d_in[3];
  const float* ab  = (const float*)d_in[4];

  float* out = (float*)d_out;                 // 8192*256
  float* att = out + (size_t)8192 * 256;      // 8192*8192

  char* ws = (char*)d_ws;
  unsigned short* ht    = (unsigned short*)ws;                              // 4 MB
  unsigned short* Wt_hi = (unsigned short*)(ws + (size_t)4 * 1024 * 1024);  // 256 KB
  unsigned short* Wt_lo = Wt_hi + (size_t)256 * 512;                        // 256 KB
  float* s1      = (float*)(ws + (size_t)4 * 1024 * 1024 + 512 * 1024);     // 32 KB
  float* e2      = s1 + 8192;
  float* e02     = e2 + 8192;
  float* rowinfo = e02 + 8192;                                              // 128 KB
  int*   cnt     = (int*)(rowinfo + 8192 * 4);                              // 512 B
  const size_t base = (size_t)5 * 1024 * 1024;
  const size_t partBytes = (size_t)NROW * DDIM * sizeof(float);             // 8 MB

  int KS = 1;
  for (int c = 4; c >= 1; c >>= 1)
    if (base + (size_t)c * partBytes <= ws_size) { KS = c; break; }
  float* part = (float*)(ws + base);
  const int CHUNK = NROW / KS;
  const size_t smem = 16384 + (size_t)2 * CHUNK * sizeof(float);

  hipLaunchKernelGGL(k_prep,   dim3(128),     dim3(256), 0,    stream, W, Wt_hi, Wt_lo, cnt);
  hipLaunchKernelGGL(k_h,      dim3(256),     dim3(512), 0,    stream, doc, Wt_hi, Wt_lo, Wb, a, ht, s1, e2, e02);
  hipLaunchKernelGGL(k_z,      dim3(512),     dim3(256), 0,    stream, s1, e2, e02, ab, rowinfo);
  hipLaunchKernelGGL(k_att,    dim3(KS, 128), dim3(512), smem, stream, rowinfo, e2, e02, ht, att, part, out, cnt, CHUNK);
}

// Round 20
// 201.180 us; speedup vs baseline: 3.0729x; 1.6147x over previous
//
#include <hip/hip_runtime.h>
#include <hip/hip_bf16.h>

// GAT layer — restructured k_att: 32 FULL rows per block (grid 256), no split-K.
// Z computed in-block (no duplication, replaces k_z), out written directly
// (replaces k_reduce), e2/e02 staged bf16 (48.5KB LDS). 3 dispatches total.
// No fences/atomics (r19 lesson: device fences trigger per-XCD L2 writeback).

typedef __attribute__((ext_vector_type(4))) float f32x4;
typedef __attribute__((ext_vector_type(8))) short short8;
typedef __attribute__((ext_vector_type(4))) unsigned short ushort4v;

#define SLOPE 0.1f
#define NROW 8192
#define DDIM 256

__device__ __forceinline__ float lrelu(float x){ return fmaxf(x, SLOPE * x); }

__device__ __forceinline__ unsigned short f2bf(float f){
  union { float f; unsigned u; } v; v.f = f;
  unsigned r = (v.u + 0x7fffu + ((v.u >> 16) & 1u)) >> 16;
  return (unsigned short)r;
}
__device__ __forceinline__ float bf2f(unsigned short u){
  union { unsigned u; float f; } v; v.u = (unsigned)u << 16; return v.f;
}
__device__ __forceinline__ unsigned cvt_pk_bf16(float lo, float hi){
  unsigned r;
  asm("v_cvt_pk_bf16_f32 %0, %1, %2" : "=v"(r) : "v"(lo), "v"(hi));
  return r;
}

// ---------------- K0: Wt_hi/Wt_lo [256][512] bf16 split-transpose of W ----------------
__global__ __launch_bounds__(256) void k_prep(
    const float* __restrict__ W,
    unsigned short* __restrict__ Wt_hi, unsigned short* __restrict__ Wt_lo)
{
  const int tid = blockIdx.x * 256 + threadIdx.x;   // 32768 total
  const int c = tid >> 7, kq = tid & 127;
  ushort4v hi, lo;
#pragma unroll
  for (int j = 0; j < 4; ++j) {
    const float v = W[(size_t)(kq * 4 + j) * 256 + c];
    hi[j] = f2bf(v);
    lo[j] = f2bf(v - bf2f(hi[j]));
  }
  *reinterpret_cast<ushort4v*>(Wt_hi + (size_t)c * 512 + kq * 4) = hi;
  *reinterpret_cast<ushort4v*>(Wt_lo + (size_t)c * 512 + kq * 4) = lo;
}

// ---------------- K1: h-tile via split MFMA; fused s1/s2/e2/e02 + ht bf16 ----------------
__global__ __launch_bounds__(512, 2) void k_h(
    const float* __restrict__ doc, const unsigned short* __restrict__ Wt_hi,
    const unsigned short* __restrict__ Wt_lo, const float* __restrict__ Wb,
    const float* __restrict__ a,
    unsigned short* __restrict__ ht, float* __restrict__ s1,
    float* __restrict__ e2, float* __restrict__ e02)
{
  __shared__ __align__(16) short8 aH[2][2][64];
  __shared__ __align__(16) short8 aL[2][2][64];
  __shared__ float sred[8][2][32];

  const int t = threadIdx.x, w = t >> 6, l = t & 63;
  const int lr = l & 15, lg = l >> 4;
  const int rb = blockIdx.x * 32;
  const int cb = w * 32;

  f32x4 acc[2][2];
#pragma unroll
  for (int rt = 0; rt < 2; ++rt)
#pragma unroll
    for (int ct = 0; ct < 2; ++ct) acc[rt][ct] = (f32x4){0.f, 0.f, 0.f, 0.f};

  const float* docp = doc + (size_t)(rb + w * 16 + lr) * 512 + lg * 8;  // valid for w<2

  f32x4 v0, v1;
  auto loadDoc = [&](int k0) { if (w < 2) {
      v0 = *reinterpret_cast<const f32x4*>(docp + k0);
      v1 = *reinterpret_cast<const f32x4*>(docp + k0 + 4);
  }};
  auto writeStage = [&](int pb) { if (w < 2) {
      union { short8 v; unsigned short u[8]; } hi, lo;
#pragma unroll
      for (int q = 0; q < 4; ++q) {
        hi.u[q] = f2bf(v0[q]);     lo.u[q] = f2bf(v0[q] - bf2f(hi.u[q]));
        hi.u[4+q] = f2bf(v1[q]);   lo.u[4+q] = f2bf(v1[q] - bf2f(hi.u[4+q]));
      }
      aH[pb][w][l] = hi.v;
      aL[pb][w][l] = lo.v;
  }};

  loadDoc(0); writeStage(0); loadDoc(32);

  for (int n = 0; n < 16; ++n) {
    const int kk = n * 32;
    const int par = n & 1;

    asm volatile("s_waitcnt lgkmcnt(0)\n\ts_barrier" ::: "memory");

    const short8 ah0 = aH[par][0][l];
    const short8 ah1 = aH[par][1][l];
    const short8 al0 = aL[par][0][l];
    const short8 al1 = aL[par][1][l];

    short8 bh[2], bl[2];
#pragma unroll
    for (int ct = 0; ct < 2; ++ct) {
      const size_t off = (size_t)(cb + ct * 16 + lr) * 512 + kk + lg * 8;
      bh[ct] = *reinterpret_cast<const short8*>(Wt_hi + off);
      bl[ct] = *reinterpret_cast<const short8*>(Wt_lo + off);
    }

    if (n + 1 < 16) writeStage(par ^ 1);
    if (n + 2 < 16) loadDoc((n + 2) * 32);

#pragma unroll
    for (int ct = 0; ct < 2; ++ct) {
      acc[0][ct] = __builtin_amdgcn_mfma_f32_16x16x32_bf16(ah0, bh[ct], acc[0][ct], 0, 0, 0);
      acc[1][ct] = __builtin_amdgcn_mfma_f32_16x16x32_bf16(ah1, bh[ct], acc[1][ct], 0, 0, 0);
      acc[0][ct] = __builtin_amdgcn_mfma_f32_16x16x32_bf16(ah0, bl[ct], acc[0][ct], 0, 0, 0);
      acc[1][ct] = __builtin_amdgcn_mfma_f32_16x16x32_bf16(ah1, bl[ct], acc[1][ct], 0, 0, 0);
      acc[0][ct] = __builtin_amdgcn_mfma_f32_16x16x32_bf16(al0, bh[ct], acc[0][ct], 0, 0, 0);
      acc[1][ct] = __builtin_amdgcn_mfma_f32_16x16x32_bf16(al1, bh[ct], acc[1][ct], 0, 0, 0);
    }
  }

  float bias[2];
#pragma unroll
  for (int ct = 0; ct < 2; ++ct) bias[ct] = Wb[cb + ct * 16 + lr];
#pragma unroll
  for (int rt = 0; rt < 2; ++rt)
#pragma unroll
    for (int ct = 0; ct < 2; ++ct) {
#pragma unroll
      for (int q = 0; q < 4; ++q) acc[rt][ct][q] += bias[ct];
      ushort4v u;
#pragma unroll
      for (int q = 0; q < 4; ++q) u[q] = f2bf(acc[rt][ct][q]);
      *reinterpret_cast<ushort4v*>(
          ht + (size_t)(cb + ct * 16 + lr) * 8192 + rb + rt * 16 + lg * 4) = u;
    }

  float a1c[2], a2c[2];
#pragma unroll
  for (int ct = 0; ct < 2; ++ct) {
    a1c[ct] = a[cb + ct * 16 + lr];
    a2c[ct] = a[256 + cb + ct * 16 + lr];
  }
  float p1[2][4], p2[2][4];
#pragma unroll
  for (int rt = 0; rt < 2; ++rt)
#pragma unroll
    for (int q = 0; q < 4; ++q) {
      float x1 = 0.f, x2 = 0.f;
#pragma unroll
      for (int ct = 0; ct < 2; ++ct) {
        x1 = fmaf(acc[rt][ct][q], a1c[ct], x1);
        x2 = fmaf(acc[rt][ct][q], a2c[ct], x2);
      }
#pragma unroll
      for (int off = 1; off < 16; off <<= 1) {
        x1 += __shfl_xor(x1, off);
        x2 += __shfl_xor(x2, off);
      }
      p1[rt][q] = x1; p2[rt][q] = x2;
    }
  __syncthreads();
  if (lr == 0) {
#pragma unroll
    for (int rt = 0; rt < 2; ++rt)
#pragma unroll
      for (int q = 0; q < 4; ++q) {
        sred[w][0][rt * 16 + lg * 4 + q] = p1[rt][q];
        sred[w][1][rt * 16 + lg * 4 + q] = p2[rt][q];
      }
  }
  __syncthreads();
  if (t < 32) {
    float v1s = 0.f, v2s = 0.f;
#pragma unroll
    for (int ww = 0; ww < 8; ++ww) { v1s += sred[ww][0][t]; v2s += sred[ww][1][t]; }
    const int r = rb + t;
    s1[r] = v1s;
    e2[r] = __expf(v2s);
    e02[r] = __expf(SLOPE * v2s);
  }
}

// ---------------- K2: att + out, 32 full rows/block, fused Z, no split-K ----------------
// grid 256, block 512 = 8 waves. Phases of 4 windows (128 k); 64 phases.
// Wave w gens window (w&3), row-set rt=w>>2 per phase; consumes all windows
// for cols w*32..+31. Phase order rotated per block (channel spread).
__global__ __launch_bounds__(512, 2) void k_att(
    const float* __restrict__ s1g, const float* __restrict__ abp,
    const float* __restrict__ e2g, const float* __restrict__ e02g,
    const unsigned short* __restrict__ ht,
    float* __restrict__ att, float* __restrict__ out)
{
  __shared__ __align__(16) unsigned short e2b[8192];    // 16 KB bf16
  __shared__ __align__(16) unsigned short e02b[8192];   // 16 KB
  __shared__ __align__(16) short8 FR[2][4][2][64];      // 16 KB frag ring
  f32x4* rowinfoL = reinterpret_cast<f32x4*>(&FR[0][0][0][0]);  // transient overlay (512 B)

  const int t = threadIdx.x, w = t >> 6, l = t & 63;
  const int lr = l & 15, lg = l >> 4;
  const int rb = blockIdx.x * 32;

  // ---- stage e2/e02 as bf16 ----
  for (int i = t * 4; i < 8192; i += 2048) {
    const f32x4 ev = *reinterpret_cast<const f32x4*>(e2g + i);
    const f32x4 fv = *reinterpret_cast<const f32x4*>(e02g + i);
    uint2 pe, pf;
    pe.x = cvt_pk_bf16(ev[0], ev[1]); pe.y = cvt_pk_bf16(ev[2], ev[3]);
    pf.x = cvt_pk_bf16(fv[0], fv[1]); pf.y = cvt_pk_bf16(fv[2], fv[3]);
    *reinterpret_cast<uint2*>(&e2b[i])  = pe;
    *reinterpret_cast<uint2*>(&e02b[i]) = pf;
  }
  __syncthreads();

  // ---- Z phase: 32 rows, 16 lanes/row ----
  {
    const int zr = t >> 4, sub = t & 15;
    const float s1a = s1g[rb + zr] + abp[0];
    const float E1 = __expf(s1a), E01 = __expf(SLOPE * s1a), Tv = __expf(-s1a);
    float zA = 0.f, zB = 0.f;
    for (int jj = sub * 512; jj < sub * 512 + 512; jj += 8) {
      const short8 eb = *reinterpret_cast<const short8*>(&e2b[jj]);
      const short8 fb = *reinterpret_cast<const short8*>(&e02b[jj]);
      union { short8 v; unsigned short u[8]; } eu, fu; eu.v = eb; fu.v = fb;
#pragma unroll
      for (int q = 0; q < 8; ++q) {
        const float e = bf2f(eu.u[q]);
        const bool c = (e >= Tv);
        zA += c ? e : 0.f;
        zB += c ? 0.f : bf2f(fu.u[q]);
      }
    }
#pragma unroll
    for (int off = 1; off < 16; off <<= 1) { zA += __shfl_xor(zA, off); zB += __shfl_xor(zB, off); }
    if (sub == 0) {
      const float z = E1 * zA + E01 * zB;
      const float iz = 1.0f / z;
      rowinfoL[zr] = (f32x4){E1 * iz, E01 * iz, Tv, iz};
    }
  }
  __syncthreads();

  // writer constants (row = rt-set*16 + lr)
  const int wrt = w >> 2;
  const int wrow = wrt * 16 + lr;
  const f32x4 wri = rowinfoL[wrow];
  const float E1z = wri[0], E01z = wri[1], T = wri[2];
  float* attW = att + (size_t)(rb + wrow) * 8192 + lg * 8;
  __syncthreads();   // rowinfo overlay read complete; FR reusable

  auto gen = [&](int q, int parw) {
    const int win = q * 4 + (w & 3);
    const int jb = win * 32 + lg * 8;
    union { short8 v; unsigned short u[8]; } eu, fu;
    eu.v = *reinterpret_cast<const short8*>(&e2b[jb]);
    fu.v = *reinterpret_cast<const short8*>(&e02b[jb]);
    f32x4 pA, pB;
#pragma unroll
    for (int qq = 0; qq < 4; ++qq) {
      const float eA = bf2f(eu.u[qq]),     fA = bf2f(fu.u[qq]);
      const float eB = bf2f(eu.u[4 + qq]), fB = bf2f(fu.u[4 + qq]);
      const bool cA = (eA >= T);
      pA[qq] = (cA ? E1z : E01z) * (cA ? eA : fA);
      const bool cB = (eB >= T);
      pB[qq] = (cB ? E1z : E01z) * (cB ? eB : fB);
    }
    __builtin_nontemporal_store(pA, reinterpret_cast<f32x4*>(attW + win * 32));
    __builtin_nontemporal_store(pB, reinterpret_cast<f32x4*>(attW + win * 32 + 4));
    union { short8 v; unsigned u[4]; } pk;
    pk.u[0] = cvt_pk_bf16(pA[0], pA[1]); pk.u[1] = cvt_pk_bf16(pA[2], pA[3]);
    pk.u[2] = cvt_pk_bf16(pB[0], pB[1]); pk.u[3] = cvt_pk_bf16(pB[2], pB[3]);
    FR[parw][w & 3][wrt][l] = pk.v;
  };

  const unsigned short* hbase = ht + (size_t)(w * 32 + lr) * 8192 + lg * 8;
  auto loadB = [&](short8* b, int m) {
    const int kk = m * 32;
    b[0] = *reinterpret_cast<const short8*>(hbase + kk);
    b[1] = *reinterpret_cast<const short8*>(hbase + kk + (size_t)16 * 8192);
  };

  f32x4 acc00 = {0,0,0,0}, acc01 = {0,0,0,0}, acc10 = {0,0,0,0}, acc11 = {0,0,0,0};

  auto mma = [&](const short8* b, int par, int u) {
    const short8* fr = &FR[par][u][0][0];
    const short8 af0 = fr[l];
    const short8 af1 = fr[64 + l];
    __builtin_amdgcn_s_setprio(1);
    acc00 = __builtin_amdgcn_mfma_f32_16x16x32_bf16(af0, b[0], acc00, 0, 0, 0);
    acc10 = __builtin_amdgcn_mfma_f32_16x16x32_bf16(af1, b[0], acc10, 0, 0, 0);
    acc01 = __builtin_amdgcn_mfma_f32_16x16x32_bf16(af0, b[1], acc01, 0, 0, 0);
    acc11 = __builtin_amdgcn_mfma_f32_16x16x32_bf16(af1, b[1], acc11, 0, 0, 0);
    __builtin_amdgcn_s_setprio(0);
  };

  const int ro = (blockIdx.x * 23) & 63;   // phase rotation (bijective mod 64)

  short8 bAr[2], bBr[2];
  const int q0 = ro;
  gen(q0, 0);
  loadB(bAr, q0 * 4);

  for (int p = 0; p < 64; ++p) {
    const int q = (p + ro) & 63;
    const int par = p & 1;
    asm volatile("s_waitcnt lgkmcnt(0)\n\ts_barrier" ::: "memory");
    if (p + 1 < 64) gen((p + 1 + ro) & 63, par ^ 1);
    loadB(bBr, q * 4 + 1);
    mma(bAr, par, 0);
    loadB(bAr, q * 4 + 2);
    mma(bBr, par, 1);
    loadB(bBr, q * 4 + 3);
    mma(bAr, par, 2);
    if (p + 1 < 64) loadB(bAr, ((p + 1 + ro) & 63) * 4);
    mma(bBr, par, 3);
  }

  // epilogue: out = lrelu(acc), direct (no split-K)
#pragma unroll
  for (int q = 0; q < 4; ++q) {
    const size_t r0 = (size_t)(rb + 0 * 16 + lg * 4 + q) * 256 + w * 32 + lr;
    const size_t r1 = (size_t)(rb + 1 * 16 + lg * 4 + q) * 256 + w * 32 + lr;
    __builtin_nontemporal_store(lrelu(acc00[q]), out + r0);
    __builtin_nontemporal_store(lrelu(acc01[q]), out + r0 + 16);
    __builtin_nontemporal_store(lrelu(acc10[q]), out + r1);
    __builtin_nontemporal_store(lrelu(acc11[q]), out + r1 + 16);
  }
}

extern "C" void kernel_launch(void* const* d_in, const int* in_sizes, int n_in,
                              void* d_out, int out_size, void* d_ws, size_t ws_size,
                              hipStream_t stream)
{
  const float* doc = (const float*)d_in[0];
  const float* W   = (const float*)d_in[1];
  const float* Wb  = (const float*)d_in[2];
  const float* a   = (const float*)d_in[3];
  const float* ab  = (const float*)d_in[4];

  float* out = (float*)d_out;                 // 8192*256
  float* att = out + (size_t)8192 * 256;      // 8192*8192

  char* ws = (char*)d_ws;
  unsigned short* ht    = (unsigned short*)ws;                              // 4 MB
  unsigned short* Wt_hi = (unsigned short*)(ws + (size_t)4 * 1024 * 1024);  // 256 KB
  unsigned short* Wt_lo = Wt_hi + (size_t)256 * 512;                        // 256 KB
  float* s1  = (float*)(ws + (size_t)4 * 1024 * 1024 + 512 * 1024);         // 32 KB
  float* e2  = s1 + 8192;
  float* e02 = e2 + 8192;

  hipLaunchKernelGGL(k_prep, dim3(128), dim3(256), 0, stream, W, Wt_hi, Wt_lo);
  hipLaunchKernelGGL(k_h,    dim3(256), dim3(512), 0, stream, doc, Wt_hi, Wt_lo, Wb, a, ht, s1, e2, e02);
  hipLaunchKernelGGL(k_att,  dim3(256), dim3(512), 0, stream, s1, ab, e2, e02, ht, att, out);
}

// Round 21
// 187.694 us; speedup vs baseline: 3.2937x; 1.0719x over previous
//
#include <hip/hip_runtime.h>
#include <hip/hip_bf16.h>

// GAT layer — r20 3-dispatch structure (fused Z + direct out, no split-K),
// k_att pipeline REPAIRED: all 8 B-frags for phase p+1 prefetched at top of
// phase p (before gen's stores -> stores never gate MFMA; full-phase latency
// hiding, restoring the r8 lesson). Z-phase LDS reads re-strided (2-way free).

typedef __attribute__((ext_vector_type(4))) float f32x4;
typedef __attribute__((ext_vector_type(8))) short short8;
typedef __attribute__((ext_vector_type(4))) unsigned short ushort4v;

#define SLOPE 0.1f
#define NROW 8192
#define DDIM 256

__device__ __forceinline__ float lrelu(float x){ return fmaxf(x, SLOPE * x); }

__device__ __forceinline__ unsigned short f2bf(float f){
  union { float f; unsigned u; } v; v.f = f;
  unsigned r = (v.u + 0x7fffu + ((v.u >> 16) & 1u)) >> 16;
  return (unsigned short)r;
}
__device__ __forceinline__ float bf2f(unsigned short u){
  union { unsigned u; float f; } v; v.u = (unsigned)u << 16; return v.f;
}
__device__ __forceinline__ unsigned cvt_pk_bf16(float lo, float hi){
  unsigned r;
  asm("v_cvt_pk_bf16_f32 %0, %1, %2" : "=v"(r) : "v"(lo), "v"(hi));
  return r;
}

// ---------------- K0: Wt_hi/Wt_lo [256][512] bf16 split-transpose of W ----------------
__global__ __launch_bounds__(256) void k_prep(
    const float* __restrict__ W,
    unsigned short* __restrict__ Wt_hi, unsigned short* __restrict__ Wt_lo)
{
  const int tid = blockIdx.x * 256 + threadIdx.x;   // 32768 total
  const int c = tid >> 7, kq = tid & 127;
  ushort4v hi, lo;
#pragma unroll
  for (int j = 0; j < 4; ++j) {
    const float v = W[(size_t)(kq * 4 + j) * 256 + c];
    hi[j] = f2bf(v);
    lo[j] = f2bf(v - bf2f(hi[j]));
  }
  *reinterpret_cast<ushort4v*>(Wt_hi + (size_t)c * 512 + kq * 4) = hi;
  *reinterpret_cast<ushort4v*>(Wt_lo + (size_t)c * 512 + kq * 4) = lo;
}

// ---------------- K1: h-tile via split MFMA; fused s1/s2/e2/e02 + ht bf16 ----------------
__global__ __launch_bounds__(512, 2) void k_h(
    const float* __restrict__ doc, const unsigned short* __restrict__ Wt_hi,
    const unsigned short* __restrict__ Wt_lo, const float* __restrict__ Wb,
    const float* __restrict__ a,
    unsigned short* __restrict__ ht, float* __restrict__ s1,
    float* __restrict__ e2, float* __restrict__ e02)
{
  __shared__ __align__(16) short8 aH[2][2][64];
  __shared__ __align__(16) short8 aL[2][2][64];
  __shared__ float sred[8][2][32];

  const int t = threadIdx.x, w = t >> 6, l = t & 63;
  const int lr = l & 15, lg = l >> 4;
  const int rb = blockIdx.x * 32;
  const int cb = w * 32;

  f32x4 acc[2][2];
#pragma unroll
  for (int rt = 0; rt < 2; ++rt)
#pragma unroll
    for (int ct = 0; ct < 2; ++ct) acc[rt][ct] = (f32x4){0.f, 0.f, 0.f, 0.f};

  const float* docp = doc + (size_t)(rb + w * 16 + lr) * 512 + lg * 8;  // valid for w<2

  f32x4 v0, v1;
  auto loadDoc = [&](int k0) { if (w < 2) {
      v0 = *reinterpret_cast<const f32x4*>(docp + k0);
      v1 = *reinterpret_cast<const f32x4*>(docp + k0 + 4);
  }};
  auto writeStage = [&](int pb) { if (w < 2) {
      union { short8 v; unsigned short u[8]; } hi, lo;
#pragma unroll
      for (int q = 0; q < 4; ++q) {
        hi.u[q] = f2bf(v0[q]);     lo.u[q] = f2bf(v0[q] - bf2f(hi.u[q]));
        hi.u[4+q] = f2bf(v1[q]);   lo.u[4+q] = f2bf(v1[q] - bf2f(hi.u[4+q]));
      }
      aH[pb][w][l] = hi.v;
      aL[pb][w][l] = lo.v;
  }};

  loadDoc(0); writeStage(0); loadDoc(32);

  for (int n = 0; n < 16; ++n) {
    const int kk = n * 32;
    const int par = n & 1;

    asm volatile("s_waitcnt lgkmcnt(0)\n\ts_barrier" ::: "memory");

    const short8 ah0 = aH[par][0][l];
    const short8 ah1 = aH[par][1][l];
    const short8 al0 = aL[par][0][l];
    const short8 al1 = aL[par][1][l];

    short8 bh[2], bl[2];
#pragma unroll
    for (int ct = 0; ct < 2; ++ct) {
      const size_t off = (size_t)(cb + ct * 16 + lr) * 512 + kk + lg * 8;
      bh[ct] = *reinterpret_cast<const short8*>(Wt_hi + off);
      bl[ct] = *reinterpret_cast<const short8*>(Wt_lo + off);
    }

    if (n + 1 < 16) writeStage(par ^ 1);
    if (n + 2 < 16) loadDoc((n + 2) * 32);

#pragma unroll
    for (int ct = 0; ct < 2; ++ct) {
      acc[0][ct] = __builtin_amdgcn_mfma_f32_16x16x32_bf16(ah0, bh[ct], acc[0][ct], 0, 0, 0);
      acc[1][ct] = __builtin_amdgcn_mfma_f32_16x16x32_bf16(ah1, bh[ct], acc[1][ct], 0, 0, 0);
      acc[0][ct] = __builtin_amdgcn_mfma_f32_16x16x32_bf16(ah0, bl[ct], acc[0][ct], 0, 0, 0);
      acc[1][ct] = __builtin_amdgcn_mfma_f32_16x16x32_bf16(ah1, bl[ct], acc[1][ct], 0, 0, 0);
      acc[0][ct] = __builtin_amdgcn_mfma_f32_16x16x32_bf16(al0, bh[ct], acc[0][ct], 0, 0, 0);
      acc[1][ct] = __builtin_amdgcn_mfma_f32_16x16x32_bf16(al1, bh[ct], acc[1][ct], 0, 0, 0);
    }
  }

  float bias[2];
#pragma unroll
  for (int ct = 0; ct < 2; ++ct) bias[ct] = Wb[cb + ct * 16 + lr];
#pragma unroll
  for (int rt = 0; rt < 2; ++rt)
#pragma unroll
    for (int ct = 0; ct < 2; ++ct) {
#pragma unroll
      for (int q = 0; q < 4; ++q) acc[rt][ct][q] += bias[ct];
      ushort4v u;
#pragma unroll
      for (int q = 0; q < 4; ++q) u[q] = f2bf(acc[rt][ct][q]);
      *reinterpret_cast<ushort4v*>(
          ht + (size_t)(cb + ct * 16 + lr) * 8192 + rb + rt * 16 + lg * 4) = u;
    }

  float a1c[2], a2c[2];
#pragma unroll
  for (int ct = 0; ct < 2; ++ct) {
    a1c[ct] = a[cb + ct * 16 + lr];
    a2c[ct] = a[256 + cb + ct * 16 + lr];
  }
  float p1[2][4], p2[2][4];
#pragma unroll
  for (int rt = 0; rt < 2; ++rt)
#pragma unroll
    for (int q = 0; q < 4; ++q) {
      float x1 = 0.f, x2 = 0.f;
#pragma unroll
      for (int ct = 0; ct < 2; ++ct) {
        x1 = fmaf(acc[rt][ct][q], a1c[ct], x1);
        x2 = fmaf(acc[rt][ct][q], a2c[ct], x2);
      }
#pragma unroll
      for (int off = 1; off < 16; off <<= 1) {
        x1 += __shfl_xor(x1, off);
        x2 += __shfl_xor(x2, off);
      }
      p1[rt][q] = x1; p2[rt][q] = x2;
    }
  __syncthreads();
  if (lr == 0) {
#pragma unroll
    for (int rt = 0; rt < 2; ++rt)
#pragma unroll
      for (int q = 0; q < 4; ++q) {
        sred[w][0][rt * 16 + lg * 4 + q] = p1[rt][q];
        sred[w][1][rt * 16 + lg * 4 + q] = p2[rt][q];
      }
  }
  __syncthreads();
  if (t < 32) {
    float v1s = 0.f, v2s = 0.f;
#pragma unroll
    for (int ww = 0; ww < 8; ++ww) { v1s += sred[ww][0][t]; v2s += sred[ww][1][t]; }
    const int r = rb + t;
    s1[r] = v1s;
    e2[r] = __expf(v2s);
    e02[r] = __expf(SLOPE * v2s);
  }
}

// ---------------- K2: att + out, 32 full rows/block, fused Z, phase-ahead B prefetch ----------------
// grid 256, block 512 = 8 waves. Phase = 4 windows (128 k); 64 phases.
// Wave w gens window (w&3), row-set wrt=w>>2; consumes cols w*32..+31.
// All 8 B-frags for phase p+1 issued at top of phase p, BEFORE gen(p+1) stores.
__global__ __launch_bounds__(512, 2) void k_att(
    const float* __restrict__ s1g, const float* __restrict__ abp,
    const float* __restrict__ e2g, const float* __restrict__ e02g,
    const unsigned short* __restrict__ ht,
    float* __restrict__ att, float* __restrict__ out)
{
  __shared__ __align__(16) unsigned short e2b[8192];    // 16 KB bf16
  __shared__ __align__(16) unsigned short e02b[8192];   // 16 KB
  __shared__ __align__(16) short8 FR[2][4][2][64];      // 16 KB frag ring
  f32x4* rowinfoL = reinterpret_cast<f32x4*>(&FR[0][0][0][0]);  // transient overlay

  const int t = threadIdx.x, w = t >> 6, l = t & 63;
  const int lr = l & 15, lg = l >> 4;
  const int rb = blockIdx.x * 32;

  // ---- stage e2/e02 as bf16 ----
  for (int i = t * 4; i < 8192; i += 2048) {
    const f32x4 ev = *reinterpret_cast<const f32x4*>(e2g + i);
    const f32x4 fv = *reinterpret_cast<const f32x4*>(e02g + i);
    uint2 pe, pf;
    pe.x = cvt_pk_bf16(ev[0], ev[1]); pe.y = cvt_pk_bf16(ev[2], ev[3]);
    pf.x = cvt_pk_bf16(fv[0], fv[1]); pf.y = cvt_pk_bf16(fv[2], fv[3]);
    *reinterpret_cast<uint2*>(&e2b[i])  = pe;
    *reinterpret_cast<uint2*>(&e02b[i]) = pf;
  }
  __syncthreads();

  // ---- Z phase: 32 rows, 16 lanes/row; strided reads (2-way bank = free) ----
  {
    const int zr = t >> 4, sub = t & 15;
    const float s1a = s1g[rb + zr] + abp[0];
    const float E1 = __expf(s1a), E01 = __expf(SLOPE * s1a), Tv = __expf(-s1a);
    float zA = 0.f, zB = 0.f;
    for (int c = 0; c < 64; ++c) {
      const int jj = c * 128 + sub * 8;
      const short8 eb = *reinterpret_cast<const short8*>(&e2b[jj]);
      const short8 fb = *reinterpret_cast<const short8*>(&e02b[jj]);
      union { short8 v; unsigned short u[8]; } eu, fu; eu.v = eb; fu.v = fb;
#pragma unroll
      for (int q = 0; q < 8; ++q) {
        const float e = bf2f(eu.u[q]);
        const bool cc = (e >= Tv);
        zA += cc ? e : 0.f;
        zB += cc ? 0.f : bf2f(fu.u[q]);
      }
    }
#pragma unroll
    for (int off = 1; off < 16; off <<= 1) { zA += __shfl_xor(zA, off); zB += __shfl_xor(zB, off); }
    if (sub == 0) {
      const float z = E1 * zA + E01 * zB;
      const float iz = 1.0f / z;
      rowinfoL[zr] = (f32x4){E1 * iz, E01 * iz, Tv, iz};
    }
  }
  __syncthreads();

  const int wrt = w >> 2;
  const int wrow = wrt * 16 + lr;
  const f32x4 wri = rowinfoL[wrow];
  const float E1z = wri[0], E01z = wri[1], T = wri[2];
  float* attW = att + (size_t)(rb + wrow) * 8192 + lg * 8;
  __syncthreads();   // rowinfo overlay read complete; FR reusable

  auto gen = [&](int q, int parw) {
    const int win = q * 4 + (w & 3);
    const int jb = win * 32 + lg * 8;
    union { short8 v; unsigned short u[8]; } eu, fu;
    eu.v = *reinterpret_cast<const short8*>(&e2b[jb]);
    fu.v = *reinterpret_cast<const short8*>(&e02b[jb]);
    f32x4 pA, pB;
#pragma unroll
    for (int qq = 0; qq < 4; ++qq) {
      const float eA = bf2f(eu.u[qq]),     fA = bf2f(fu.u[qq]);
      const float eB = bf2f(eu.u[4 + qq]), fB = bf2f(fu.u[4 + qq]);
      const bool cA = (eA >= T);
      pA[qq] = (cA ? E1z : E01z) * (cA ? eA : fA);
      const bool cB = (eB >= T);
      pB[qq] = (cB ? E1z : E01z) * (cB ? eB : fB);
    }
    __builtin_nontemporal_store(pA, reinterpret_cast<f32x4*>(attW + win * 32));
    __builtin_nontemporal_store(pB, reinterpret_cast<f32x4*>(attW + win * 32 + 4));
    union { short8 v; unsigned u[4]; } pk;
    pk.u[0] = cvt_pk_bf16(pA[0], pA[1]); pk.u[1] = cvt_pk_bf16(pA[2], pA[3]);
    pk.u[2] = cvt_pk_bf16(pB[0], pB[1]); pk.u[3] = cvt_pk_bf16(pB[2], pB[3]);
    FR[parw][w & 3][wrt][l] = pk.v;
  };

  const unsigned short* hbase = ht + (size_t)(w * 32 + lr) * 8192 + lg * 8;
  // load all 8 B-frags for phase q (4 windows x 2 col-tiles)
  auto loadB8 = [&](short8* b, int q) {
#pragma unroll
    for (int u = 0; u < 4; ++u) {
      const int kk = (q * 4 + u) * 32;
      b[2 * u]     = *reinterpret_cast<const short8*>(hbase + kk);
      b[2 * u + 1] = *reinterpret_cast<const short8*>(hbase + kk + (size_t)16 * 8192);
    }
  };

  f32x4 acc00 = {0,0,0,0}, acc01 = {0,0,0,0}, acc10 = {0,0,0,0}, acc11 = {0,0,0,0};

  auto mma = [&](const short8& b0, const short8& b1, int par, int u) {
    const short8* fr = &FR[par][u][0][0];
    const short8 af0 = fr[l];
    const short8 af1 = fr[64 + l];
    __builtin_amdgcn_s_setprio(1);
    acc00 = __builtin_amdgcn_mfma_f32_16x16x32_bf16(af0, b0, acc00, 0, 0, 0);
    acc10 = __builtin_amdgcn_mfma_f32_16x16x32_bf16(af1, b0, acc10, 0, 0, 0);
    acc01 = __builtin_amdgcn_mfma_f32_16x16x32_bf16(af0, b1, acc01, 0, 0, 0);
    acc11 = __builtin_amdgcn_mfma_f32_16x16x32_bf16(af1, b1, acc11, 0, 0, 0);
    __builtin_amdgcn_s_setprio(0);
  };

  const int ro = (blockIdx.x * 23) & 63;   // phase rotation

  short8 bA[8], bB[8];
  loadB8(bA, ro);        // phase 0 loads issued before phase 0's gen stores
  gen(ro, 0);

  for (int p = 0; p < 64; p += 2) {
    // phase p (even): frags FR[0], regs bA
    asm volatile("s_waitcnt lgkmcnt(0)\n\ts_barrier" ::: "memory");
    if (p + 1 < 64) loadB8(bB, (p + 1 + ro) & 63);   // before gen's stores
    if (p + 1 < 64) gen((p + 1 + ro) & 63, 1);
    mma(bA[0], bA[1], 0, 0);
    mma(bA[2], bA[3], 0, 1);
    mma(bA[4], bA[5], 0, 2);
    mma(bA[6], bA[7], 0, 3);
    if (p + 1 >= 64) break;
    // phase p+1 (odd): frags FR[1], regs bB
    asm volatile("s_waitcnt lgkmcnt(0)\n\ts_barrier" ::: "memory");
    if (p + 2 < 64) loadB8(bA, (p + 2 + ro) & 63);
    if (p + 2 < 64) gen((p + 2 + ro) & 63, 0);
    mma(bB[0], bB[1], 1, 0);
    mma(bB[2], bB[3], 1, 1);
    mma(bB[4], bB[5], 1, 2);
    mma(bB[6], bB[7], 1, 3);
  }

  // epilogue: out = lrelu(acc), direct
#pragma unroll
  for (int q = 0; q < 4; ++q) {
    const size_t r0 = (size_t)(rb + 0 * 16 + lg * 4 + q) * 256 + w * 32 + lr;
    const size_t r1 = (size_t)(rb + 1 * 16 + lg * 4 + q) * 256 + w * 32 + lr;
    __builtin_nontemporal_store(lrelu(acc00[q]), out + r0);
    __builtin_nontemporal_store(lrelu(acc01[q]), out + r0 + 16);
    __builtin_nontemporal_store(lrelu(acc10[q]), out + r1);
    __builtin_nontemporal_store(lrelu(acc11[q]), out + r1 + 16);
  }
}

extern "C" void kernel_launch(void* const* d_in, const int* in_sizes, int n_in,
                              void* d_out, int out_size, void* d_ws, size_t ws_size,
                              hipStream_t stream)
{
  const float* doc = (const float*)d_in[0];
  const float* W   = (const float*)d_in[1];
  const float* Wb  = (const float*)d_in[2];
  const float* a   = (const float*)d_in[3];
  const float* ab  = (const float*)d_in[4];

  float* out = (float*)d_out;                 // 8192*256
  float* att = out + (size_t)8192 * 256;      // 8192*8192

  char* ws = (char*)d_ws;
  unsigned short* ht    = (unsigned short*)ws;                              // 4 MB
  unsigned short* Wt_hi = (unsigned short*)(ws + (size_t)4 * 1024 * 1024);  // 256 KB
  unsigned short* Wt_lo = Wt_hi + (size_t)256 * 512;                        // 256 KB
  float* s1  = (float*)(ws + (size_t)4 * 1024 * 1024 + 512 * 1024);         // 32 KB
  float* e2  = s1 + 8192;
  float* e02 = e2 + 8192;

  hipLaunchKernelGGL(k_prep, dim3(128), dim3(256), 0, stream, W, Wt_hi, Wt_lo);
  hipLaunchKernelGGL(k_h,    dim3(256), dim3(512), 0, stream, doc, Wt_hi, Wt_lo, Wb, a, ht, s1, e2, e02);
  hipLaunchKernelGGL(k_att,  dim3(256), dim3(512), 0, stream, s1, ab, e2, e02, ht, att, out);
}

// Round 22
// 127.930 us; speedup vs baseline: 4.8324x; 1.4672x over previous
//
#include <hip/hip_runtime.h>
#include <hip/hip_bf16.h>

// GAT layer — BEST configuration (r17, 126.8 us): h via bf16-split MFMA with
// fused s1/s2/e2/e02; k_z select-trick (no exp in N^2); k_att with gen2
// 256-B/row bursts, per-block rotated k-order (HBM channel spread), window-
// ahead B reg-prefetch (stores never gate MFMA via shared vmcnt), lgkm-only
// barriers; KS=4 split-K + k_reduce. Restored after r19-r21 fusion attempts
// all regressed (device fences force per-XCD L2 writeback; full-row fusion
// collapses the pipeline overlap).

typedef __attribute__((ext_vector_type(4))) float f32x4;
typedef __attribute__((ext_vector_type(8))) short short8;
typedef __attribute__((ext_vector_type(4))) unsigned short ushort4v;

#define SLOPE 0.1f
#define NROW 8192
#define DDIM 256

__device__ __forceinline__ float lrelu(float x){ return fmaxf(x, SLOPE * x); }

__device__ __forceinline__ unsigned short f2bf(float f){
  union { float f; unsigned u; } v; v.f = f;
  unsigned r = (v.u + 0x7fffu + ((v.u >> 16) & 1u)) >> 16;
  return (unsigned short)r;
}
__device__ __forceinline__ float bf2f(unsigned short u){
  union { unsigned u; float f; } v; v.u = (unsigned)u << 16; return v.f;
}
__device__ __forceinline__ unsigned cvt_pk_bf16(float lo, float hi){
  unsigned r;
  asm("v_cvt_pk_bf16_f32 %0, %1, %2" : "=v"(r) : "v"(lo), "v"(hi));
  return r;
}

// ---------------- K0: Wt_hi/Wt_lo [256][512] bf16 split-transpose of W ----------------
__global__ __launch_bounds__(256) void k_prep(
    const float* __restrict__ W,
    unsigned short* __restrict__ Wt_hi, unsigned short* __restrict__ Wt_lo)
{
  const int tid = blockIdx.x * 256 + threadIdx.x;   // 32768 total
  const int c = tid >> 7, kq = tid & 127;
  ushort4v hi, lo;
#pragma unroll
  for (int j = 0; j < 4; ++j) {
    const float v = W[(size_t)(kq * 4 + j) * 256 + c];
    hi[j] = f2bf(v);
    lo[j] = f2bf(v - bf2f(hi[j]));
  }
  *reinterpret_cast<ushort4v*>(Wt_hi + (size_t)c * 512 + kq * 4) = hi;
  *reinterpret_cast<ushort4v*>(Wt_lo + (size_t)c * 512 + kq * 4) = lo;
}

// ---------------- K1: h-tile via split MFMA; fused s1/s2/e2/e02 + ht bf16 ----------------
__global__ __launch_bounds__(512, 2) void k_h(
    const float* __restrict__ doc, const unsigned short* __restrict__ Wt_hi,
    const unsigned short* __restrict__ Wt_lo, const float* __restrict__ Wb,
    const float* __restrict__ a,
    unsigned short* __restrict__ ht, float* __restrict__ s1,
    float* __restrict__ e2, float* __restrict__ e02)
{
  __shared__ __align__(16) short8 aH[2][2][64];
  __shared__ __align__(16) short8 aL[2][2][64];
  __shared__ float sred[8][2][32];

  const int t = threadIdx.x, w = t >> 6, l = t & 63;
  const int lr = l & 15, lg = l >> 4;
  const int rb = blockIdx.x * 32;
  const int cb = w * 32;

  f32x4 acc[2][2];
#pragma unroll
  for (int rt = 0; rt < 2; ++rt)
#pragma unroll
    for (int ct = 0; ct < 2; ++ct) acc[rt][ct] = (f32x4){0.f, 0.f, 0.f, 0.f};

  const float* docp = doc + (size_t)(rb + w * 16 + lr) * 512 + lg * 8;  // valid for w<2

  f32x4 v0, v1;
  auto loadDoc = [&](int k0) { if (w < 2) {
      v0 = *reinterpret_cast<const f32x4*>(docp + k0);
      v1 = *reinterpret_cast<const f32x4*>(docp + k0 + 4);
  }};
  auto writeStage = [&](int pb) { if (w < 2) {
      union { short8 v; unsigned short u[8]; } hi, lo;
#pragma unroll
      for (int q = 0; q < 4; ++q) {
        hi.u[q] = f2bf(v0[q]);     lo.u[q] = f2bf(v0[q] - bf2f(hi.u[q]));
        hi.u[4+q] = f2bf(v1[q]);   lo.u[4+q] = f2bf(v1[q] - bf2f(hi.u[4+q]));
      }
      aH[pb][w][l] = hi.v;
      aL[pb][w][l] = lo.v;
  }};

  loadDoc(0); writeStage(0); loadDoc(32);

  for (int n = 0; n < 16; ++n) {
    const int kk = n * 32;
    const int par = n & 1;

    asm volatile("s_waitcnt lgkmcnt(0)\n\ts_barrier" ::: "memory");

    const short8 ah0 = aH[par][0][l];
    const short8 ah1 = aH[par][1][l];
    const short8 al0 = aL[par][0][l];
    const short8 al1 = aL[par][1][l];

    short8 bh[2], bl[2];
#pragma unroll
    for (int ct = 0; ct < 2; ++ct) {
      const size_t off = (size_t)(cb + ct * 16 + lr) * 512 + kk + lg * 8;
      bh[ct] = *reinterpret_cast<const short8*>(Wt_hi + off);
      bl[ct] = *reinterpret_cast<const short8*>(Wt_lo + off);
    }

    if (n + 1 < 16) writeStage(par ^ 1);
    if (n + 2 < 16) loadDoc((n + 2) * 32);

#pragma unroll
    for (int ct = 0; ct < 2; ++ct) {
      acc[0][ct] = __builtin_amdgcn_mfma_f32_16x16x32_bf16(ah0, bh[ct], acc[0][ct], 0, 0, 0);
      acc[1][ct] = __builtin_amdgcn_mfma_f32_16x16x32_bf16(ah1, bh[ct], acc[1][ct], 0, 0, 0);
      acc[0][ct] = __builtin_amdgcn_mfma_f32_16x16x32_bf16(ah0, bl[ct], acc[0][ct], 0, 0, 0);
      acc[1][ct] = __builtin_amdgcn_mfma_f32_16x16x32_bf16(ah1, bl[ct], acc[1][ct], 0, 0, 0);
      acc[0][ct] = __builtin_amdgcn_mfma_f32_16x16x32_bf16(al0, bh[ct], acc[0][ct], 0, 0, 0);
      acc[1][ct] = __builtin_amdgcn_mfma_f32_16x16x32_bf16(al1, bh[ct], acc[1][ct], 0, 0, 0);
    }
  }

  float bias[2];
#pragma unroll
  for (int ct = 0; ct < 2; ++ct) bias[ct] = Wb[cb + ct * 16 + lr];
#pragma unroll
  for (int rt = 0; rt < 2; ++rt)
#pragma unroll
    for (int ct = 0; ct < 2; ++ct) {
#pragma unroll
      for (int q = 0; q < 4; ++q) acc[rt][ct][q] += bias[ct];
      ushort4v u;
#pragma unroll
      for (int q = 0; q < 4; ++q) u[q] = f2bf(acc[rt][ct][q]);
      *reinterpret_cast<ushort4v*>(
          ht + (size_t)(cb + ct * 16 + lr) * 8192 + rb + rt * 16 + lg * 4) = u;
    }

  float a1c[2], a2c[2];
#pragma unroll
  for (int ct = 0; ct < 2; ++ct) {
    a1c[ct] = a[cb + ct * 16 + lr];
    a2c[ct] = a[256 + cb + ct * 16 + lr];
  }
  float p1[2][4], p2[2][4];
#pragma unroll
  for (int rt = 0; rt < 2; ++rt)
#pragma unroll
    for (int q = 0; q < 4; ++q) {
      float x1 = 0.f, x2 = 0.f;
#pragma unroll
      for (int ct = 0; ct < 2; ++ct) {
        x1 = fmaf(acc[rt][ct][q], a1c[ct], x1);
        x2 = fmaf(acc[rt][ct][q], a2c[ct], x2);
      }
#pragma unroll
      for (int off = 1; off < 16; off <<= 1) {
        x1 += __shfl_xor(x1, off);
        x2 += __shfl_xor(x2, off);
      }
      p1[rt][q] = x1; p2[rt][q] = x2;
    }
  __syncthreads();
  if (lr == 0) {
#pragma unroll
    for (int rt = 0; rt < 2; ++rt)
#pragma unroll
      for (int q = 0; q < 4; ++q) {
        sred[w][0][rt * 16 + lg * 4 + q] = p1[rt][q];
        sred[w][1][rt * 16 + lg * 4 + q] = p2[rt][q];
      }
  }
  __syncthreads();
  if (t < 32) {
    float v1s = 0.f, v2s = 0.f;
#pragma unroll
    for (int ww = 0; ww < 8; ++ww) { v1s += sred[ww][0][t]; v2s += sred[ww][1][t]; }
    const int r = rb + t;
    s1[r] = v1s;
    e2[r] = __expf(v2s);
    e02[r] = __expf(SLOPE * v2s);
  }
}

// ---------------- K3: per-row Z -> rowinfo {E1*iz, E01*iz, T, iz} ----------------
__global__ __launch_bounds__(256) void k_z(
    const float* __restrict__ s1, const float* __restrict__ e2g,
    const float* __restrict__ e02g, const float* __restrict__ abp,
    float* __restrict__ rowinfo)
{
  __shared__ __align__(16) float es[8192];
  __shared__ __align__(16) float fs[8192];
  const int t = threadIdx.x;
  for (int i = t * 4; i < 8192; i += 1024) {
    *reinterpret_cast<f32x4*>(&es[i]) = *reinterpret_cast<const f32x4*>(e2g + i);
    *reinterpret_cast<f32x4*>(&fs[i]) = *reinterpret_cast<const f32x4*>(e02g + i);
  }
  __syncthreads();
  const int w = t >> 6, l = t & 63;
  const float ab = abp[0];
  const int rb = blockIdx.x * 16 + w * 4;
  float T[4], E1[4], E01[4];
#pragma unroll
  for (int rr = 0; rr < 4; ++rr) {
    const float s1a = s1[rb + rr] + ab;
    E1[rr] = __expf(s1a); E01[rr] = __expf(SLOPE * s1a); T[rr] = __expf(-s1a);
  }
  float zA[4] = {0.f,0.f,0.f,0.f}, zB[4] = {0.f,0.f,0.f,0.f};
  for (int i = l * 4; i < 8192; i += 256) {
    const f32x4 e = *reinterpret_cast<const f32x4*>(&es[i]);
    const f32x4 f = *reinterpret_cast<const f32x4*>(&fs[i]);
#pragma unroll
    for (int rr = 0; rr < 4; ++rr)
#pragma unroll
      for (int q = 0; q < 4; ++q) {
        const bool c = (e[q] >= T[rr]);
        zA[rr] += c ? e[q] : 0.f;
        zB[rr] += c ? 0.f : f[q];
      }
  }
#pragma unroll
  for (int rr = 0; rr < 4; ++rr) {
    float z = E1[rr] * zA[rr] + E01[rr] * zB[rr];
#pragma unroll
    for (int off = 32; off > 0; off >>= 1) z += __shfl_down(z, off);
    if (l == 0) {
      const float iz = 1.0f / z;
      f32x4 ri = (f32x4){E1[rr] * iz, E01[rr] * iz, T[rr], iz};
      *reinterpret_cast<f32x4*>(rowinfo + (size_t)(rb + rr) * 4) = ri;
    }
  }
}

// ---------------- K4: att + partial out via MFMA; gen2 bursts + rotated k-order ----------------
// grid (KS, 128), block 512 = 8 waves. 64 rows/block, 32-k windows, pairs.
// Per-block rotation ro decorrelates the k-phase across blocks (channel spread).
__global__ __launch_bounds__(512, 4) void k_att(
    const float* __restrict__ rowinfo, const float* __restrict__ e2g,
    const float* __restrict__ e02g, const unsigned short* __restrict__ ht,
    float* __restrict__ att, float* __restrict__ part, int CHUNK)
{
  extern __shared__ __align__(16) char smem[];
  char* plsb  = smem;                                    // [4][4][64] short8 = 16 KB
  float* e2s  = reinterpret_cast<float*>(smem + 16384);  // CHUNK
  float* e02s = e2s + CHUNK;                             // CHUNK

  const int t = threadIdx.x, w = t >> 6, l = t & 63;
  const int lr = l & 15, lg = l >> 4;
  const int kbase = blockIdx.x * CHUNK;     // slice (fastest -> XCD)
  const int rb = blockIdx.y * 64;

  for (int i = t * 4; i < CHUNK; i += 2048) {
    *reinterpret_cast<f32x4*>(e2s + i)  = *reinterpret_cast<const f32x4*>(e2g + kbase + i);
    *reinterpret_cast<f32x4*>(e02s + i) = *reinterpret_cast<const f32x4*>(e02g + kbase + i);
  }

  const int r = l >> 3, jc = l & 7;
  const int rowW = rb + w * 8 + r;
  const f32x4 ri = *reinterpret_cast<const f32x4*>(rowinfo + (size_t)rowW * 4);
  const float E1z = ri[0], E01z = ri[1], T = ri[2];
  float* attW = att + (size_t)rowW * 8192 + kbase + jc * 4;
  const int fragoff = (w >> 1) * 1024 + ((jc >> 1) * 16 + (w & 1) * 8 + r) * 16 + (jc & 1) * 8;

  __syncthreads();

  // gen2: windows kw, kw+32 (-> bufs pb0, pb1); 256 B contiguous per row
  auto gen2 = [&](int kw, int pb0, int pb1) {
    const f32x4 eA = *reinterpret_cast<const f32x4*>(e2s + kw + jc * 4);
    const f32x4 fA = *reinterpret_cast<const f32x4*>(e02s + kw + jc * 4);
    const f32x4 eB = *reinterpret_cast<const f32x4*>(e2s + kw + 32 + jc * 4);
    const f32x4 fB = *reinterpret_cast<const f32x4*>(e02s + kw + 32 + jc * 4);
    f32x4 pA, pB;
#pragma unroll
    for (int q = 0; q < 4; ++q) {
      const bool cA = (eA[q] >= T);
      pA[q] = (cA ? E1z : E01z) * (cA ? eA[q] : fA[q]);
      const bool cB = (eB[q] >= T);
      pB[q] = (cB ? E1z : E01z) * (cB ? eB[q] : fB[q]);
    }
    __builtin_nontemporal_store(pA, reinterpret_cast<f32x4*>(attW + kw));
    __builtin_nontemporal_store(pB, reinterpret_cast<f32x4*>(attW + kw + 32));
    uint2 uA, uB;
    uA.x = cvt_pk_bf16(pA[0], pA[1]); uA.y = cvt_pk_bf16(pA[2], pA[3]);
    uB.x = cvt_pk_bf16(pB[0], pB[1]); uB.y = cvt_pk_bf16(pB[2], pB[3]);
    *reinterpret_cast<uint2*>(plsb + pb0 * 4096 + fragoff) = uA;
    *reinterpret_cast<uint2*>(plsb + pb1 * 4096 + fragoff) = uB;
  };

  const unsigned short* hbase = ht + (size_t)(w * 32 + lr) * 8192 + kbase + lg * 8;
  auto loadB = [&](short8* b, int n) {
    const int kk = n * 32;
    b[0] = *reinterpret_cast<const short8*>(hbase + kk);
    b[1] = *reinterpret_cast<const short8*>(hbase + kk + (size_t)16 * 8192);
  };

  f32x4 acc[4][2];
#pragma unroll
  for (int rt = 0; rt < 4; ++rt)
#pragma unroll
    for (int ct = 0; ct < 2; ++ct) acc[rt][ct] = (f32x4){0.f, 0.f, 0.f, 0.f};

  auto mma = [&](const short8* b, const short8& af0, const short8& af1,
                 const short8& af2, const short8& af3) {
    __builtin_amdgcn_s_setprio(1);
    acc[0][0] = __builtin_amdgcn_mfma_f32_16x16x32_bf16(af0, b[0], acc[0][0], 0, 0, 0);
    acc[1][0] = __builtin_amdgcn_mfma_f32_16x16x32_bf16(af1, b[0], acc[1][0], 0, 0, 0);
    acc[2][0] = __builtin_amdgcn_mfma_f32_16x16x32_bf16(af2, b[0], acc[2][0], 0, 0, 0);
    acc[3][0] = __builtin_amdgcn_mfma_f32_16x16x32_bf16(af3, b[0], acc[3][0], 0, 0, 0);
    acc[0][1] = __builtin_amdgcn_mfma_f32_16x16x32_bf16(af0, b[1], acc[0][1], 0, 0, 0);
    acc[1][1] = __builtin_amdgcn_mfma_f32_16x16x32_bf16(af1, b[1], acc[1][1], 0, 0, 0);
    acc[2][1] = __builtin_amdgcn_mfma_f32_16x16x32_bf16(af2, b[1], acc[2][1], 0, 0, 0);
    acc[3][1] = __builtin_amdgcn_mfma_f32_16x16x32_bf16(af3, b[1], acc[3][1], 0, 0, 0);
    __builtin_amdgcn_s_setprio(0);
  };

  const int NIT = CHUNK / 32;                 // even (64 at KS=4)
  const int ro = ((blockIdx.y * 29) % (NIT / 2)) * 2;
  auto MW = [&](int n) { return (n + ro) % NIT; };

  short8 bAr[2], bBr[2];
  loadB(bAr, MW(0));
  gen2(MW(0) * 32, 0, 1);

  for (int n = 0; n < NIT; n += 2) {
    loadB(bBr, MW(n + 1));
    asm volatile("s_waitcnt lgkmcnt(0)\n\ts_barrier" ::: "memory");
    {
      const short8* pbuf = reinterpret_cast<const short8*>(plsb + (size_t)(n & 3) * 4096);
      const short8 af0 = pbuf[0 * 64 + l];
      const short8 af1 = pbuf[1 * 64 + l];
      const short8 af2 = pbuf[2 * 64 + l];
      const short8 af3 = pbuf[3 * 64 + l];
      if (n + 2 < NIT) gen2(MW(n + 2) * 32, (n + 2) & 3, (n + 3) & 3);
      mma(bAr, af0, af1, af2, af3);
    }
    if (n + 2 < NIT) loadB(bAr, MW(n + 2));
    asm volatile("s_waitcnt lgkmcnt(0)\n\ts_barrier" ::: "memory");
    {
      const short8* pbuf = reinterpret_cast<const short8*>(plsb + (size_t)((n + 1) & 3) * 4096);
      const short8 af0 = pbuf[0 * 64 + l];
      const short8 af1 = pbuf[1 * 64 + l];
      const short8 af2 = pbuf[2 * 64 + l];
      const short8 af3 = pbuf[3 * 64 + l];
      mma(bBr, af0, af1, af2, af3);
    }
  }

  float* pb = part + (size_t)blockIdx.x * ((size_t)NROW * DDIM);
#pragma unroll
  for (int rt = 0; rt < 4; ++rt)
#pragma unroll
    for (int ct = 0; ct < 2; ++ct)
#pragma unroll
      for (int q = 0; q < 4; ++q)
        __builtin_nontemporal_store(acc[rt][ct][q],
            pb + (size_t)(rb + rt * 16 + lg * 4 + q) * 256 + w * 32 + ct * 16 + lr);
}

// ---------------- K5: out = lrelu(sum_k part[k]) ----------------
__global__ __launch_bounds__(256) void k_reduce(
    const float* __restrict__ part, float* __restrict__ out, int KS)
{
  const size_t idx = ((size_t)blockIdx.x * 256 + threadIdx.x) * 4;
  f32x4 s = __builtin_nontemporal_load(reinterpret_cast<const f32x4*>(part + idx));
  for (int k = 1; k < KS; ++k) {
    const f32x4 v = __builtin_nontemporal_load(
        reinterpret_cast<const f32x4*>(part + (size_t)k * NROW * DDIM + idx));
#pragma unroll
    for (int q = 0; q < 4; ++q) s[q] += v[q];
  }
#pragma unroll
  for (int q = 0; q < 4; ++q) s[q] = lrelu(s[q]);
  __builtin_nontemporal_store(s, reinterpret_cast<f32x4*>(out + idx));
}

extern "C" void kernel_launch(void* const* d_in, const int* in_sizes, int n_in,
                              void* d_out, int out_size, void* d_ws, size_t ws_size,
                              hipStream_t stream)
{
  const float* doc = (const float*)d_in[0];
  const float* W   = (const float*)d_in[1];
  const float* Wb  = (const float*)d_in[2];
  const float* a   = (const float*)d_in[3];
  const float* ab  = (const float*)d_in[4];

  float* out = (float*)d_out;                 // 8192*256
  float* att = out + (size_t)8192 * 256;      // 8192*8192

  char* ws = (char*)d_ws;
  unsigned short* ht    = (unsigned short*)ws;                              // 4 MB
  unsigned short* Wt_hi = (unsigned short*)(ws + (size_t)4 * 1024 * 1024);  // 256 KB
  unsigned short* Wt_lo = Wt_hi + (size_t)256 * 512;                        // 256 KB
  float* s1      = (float*)(ws + (size_t)4 * 1024 * 1024 + 512 * 1024);     // 32 KB
  float* e2      = s1 + 8192;
  float* e02     = e2 + 8192;
  float* rowinfo = e02 + 8192;                                              // 128 KB
  const size_t base = (size_t)5 * 1024 * 1024;
  const size_t partBytes = (size_t)NROW * DDIM * sizeof(float);             // 8 MB

  int KS = 1;
  for (int c = 4; c >= 1; c >>= 1)
    if (base + (size_t)c * partBytes <= ws_size) { KS = c; break; }
  float* part = (float*)(ws + base);
  const int CHUNK = NROW / KS;
  const size_t smem = 16384 + (size_t)2 * CHUNK * sizeof(float);

  hipLaunchKernelGGL(k_prep,   dim3(128),     dim3(256), 0,    stream, W, Wt_hi, Wt_lo);
  hipLaunchKernelGGL(k_h,      dim3(256),     dim3(512), 0,    stream, doc, Wt_hi, Wt_lo, Wb, a, ht, s1, e2, e02);
  hipLaunchKernelGGL(k_z,      dim3(512),     dim3(256), 0,    stream, s1, e2, e02, ab, rowinfo);
  hipLaunchKernelGGL(k_att,    dim3(KS, 128), dim3(512), smem, stream, rowinfo, e2, e02, ht, att, part, CHUNK);
  hipLaunchKernelGGL(k_reduce, dim3(2048),    dim3(256), 0,    stream, part, out, KS);
}